// Round 15
// baseline (2064.226 us; speedup 1.0000x reference)
//
#include <hip/hip_runtime.h>
#include <hip/hip_bf16.h>

typedef unsigned short u16;
typedef __bf16 bf16x8 __attribute__((ext_vector_type(8)));
typedef float f32x4 __attribute__((ext_vector_type(4)));
typedef unsigned short u16x8 __attribute__((ext_vector_type(8)));

constexpr int DIMC = 2048;
constexpr int SEQ = 2048;
constexpr int NHEAD = 16;
constexpr int HDIM = 128;
constexpr int NEXP = 4;
constexpr int HIDC = 5632;
constexpr int HSH = 2816;
constexpr int MOD6 = 6 * DIMC;
constexpr int RSTRIDE = 2304;

static __device__ __forceinline__ u16 f2bf(float f) {
  __hip_bfloat16 b = __float2bfloat16(f);
  return __builtin_bit_cast(u16, b);
}
static __device__ __forceinline__ float bf2f(u16 u) {
  unsigned int x = ((unsigned int)u) << 16;
  return __builtin_bit_cast(float, x);
}
static __device__ __forceinline__ float sigf(float x) { return 1.f / (1.f + __expf(-x)); }
static __device__ __forceinline__ void splitf(float f, u16& h, u16& l) {
  h = f2bf(f);
  l = f2bf(f - bf2f(h));
}

static __device__ __forceinline__ void gload16(const void* src, void* dst) {
  __builtin_amdgcn_global_load_lds((const __attribute__((address_space(1))) void*)src,
                                   (__attribute__((address_space(3))) void*)dst, 16, 0, 0);
}

// chunked XCD swizzle, BY-FASTEST decode (requires nwg % 8 == 0; bijective).
static __device__ __forceinline__ void xcd_swz(int& bx, int& by, int& bz) {
  const int nx = gridDim.x, ny = gridDim.y;
  const int flat = blockIdx.x + nx * (blockIdx.y + ny * blockIdx.z);
  const int nwg = nx * ny * gridDim.z;
  const int swz = (flat & 7) * (nwg >> 3) + (flat >> 3);
  by = swz % ny;
  const int t = swz / ny;
  bx = t % nx;
  bz = t / nx;
}

// block = 256 threads (4 waves); returns total across block to all threads
static __device__ __forceinline__ float blockSum(float v) {
#pragma unroll
  for (int m = 1; m < 64; m <<= 1) v += __shfl_xor(v, m);
  __shared__ float s[4];
  int w = threadIdx.x >> 6;
  if ((threadIdx.x & 63) == 0) s[w] = v;
  __syncthreads();
  float r = s[0] + s[1] + s[2] + s[3];
  __syncthreads();
  return r;
}

// ---------------- transpose f32 [R,C] (row stride ldin) -> bf16 [C,R]; z-batched ----------------
__global__ __launch_bounds__(256) void k_transpose(const float* __restrict__ in, u16* __restrict__ out,
                                                   int R, int C, int ldin, size_t inz, size_t outz) {
  __shared__ __align__(16) float tile[32][33];
  const float* inp = in + (size_t)blockIdx.z * inz;
  u16* outp = out + (size_t)blockIdx.z * outz;
  int tx = threadIdx.x & 31, ty = threadIdx.x >> 5;
  int c0 = blockIdx.x * 32, r0 = blockIdx.y * 32;
#pragma unroll
  for (int i = 0; i < 32; i += 8)
    tile[ty + i][tx] = inp[(size_t)(r0 + ty + i) * ldin + c0 + tx];
  __syncthreads();
#pragma unroll
  for (int i = 0; i < 32; i += 8)
    outp[(size_t)(c0 + ty + i) * R + r0 + tx] = f2bf(tile[tx][ty + i]);
}

// ---------------- transpose f32 [R,C] -> split bf16 hi/lo [C,R] ----------------
__global__ __launch_bounds__(256) void k_transpose_s(const float* __restrict__ in, u16* __restrict__ outh,
                                                     u16* __restrict__ outl, int R, int C, int ldin) {
  __shared__ __align__(16) float tile[32][33];
  int tx = threadIdx.x & 31, ty = threadIdx.x >> 5;
  int c0 = blockIdx.x * 32, r0 = blockIdx.y * 32;
#pragma unroll
  for (int i = 0; i < 32; i += 8)
    tile[ty + i][tx] = in[(size_t)(r0 + ty + i) * ldin + c0 + tx];
  __syncthreads();
#pragma unroll
  for (int i = 0; i < 32; i += 8) {
    float v = tile[tx][ty + i];
    u16 h, l;
    splitf(v, h, l);
    size_t idx = (size_t)(c0 + ty + i) * R + r0 + tx;
    outh[idx] = h;
    outl[idx] = l;
  }
}

// ---------------- adaLN: mod = silu(a) @ W_ada + b_ada, split over 16 d-slices ----------------
__global__ __launch_bounds__(256) void k_adaln_p(const float* __restrict__ a, const float* __restrict__ W,
                                                 float* __restrict__ partial) {
  __shared__ float sa[128];
  int tid = threadIdx.x, slice = blockIdx.y;
  if (tid < 128) { float v = a[slice * 128 + tid]; sa[tid] = v * sigf(v); }
  __syncthreads();
  int j = blockIdx.x * 256 + tid;
  float acc = 0.f;
#pragma unroll 4
  for (int d = 0; d < 128; ++d) acc += sa[d] * W[(size_t)(slice * 128 + d) * MOD6 + j];
  partial[(size_t)slice * MOD6 + j] = acc;
}
__global__ __launch_bounds__(256) void k_adaln_r(const float* __restrict__ partial, const float* __restrict__ b,
                                                 float* __restrict__ mod) {
  int j = blockIdx.x * 256 + threadIdx.x;
  float acc = b[j];
#pragma unroll
  for (int s = 0; s < 16; ++s) acc += partial[(size_t)s * MOD6 + j];
  mod[j] = acc;
}

// ---------------- LayerNorm + adaLN modulate -> split hi/lo bf16 (attention x) ----------------
__global__ __launch_bounds__(256) void k_ln_mod_split(const float* __restrict__ X, const float* __restrict__ mod,
                                                      int shOff, int scOff, u16* __restrict__ outh,
                                                      u16* __restrict__ outl) {
  int row = blockIdx.x, tid = threadIdx.x;
  const float4* x4 = (const float4*)(X + (size_t)row * DIMC);
  float4 v0 = x4[tid * 2], v1 = x4[tid * 2 + 1];
  float s = v0.x + v0.y + v0.z + v0.w + v1.x + v1.y + v1.z + v1.w;
  float ss = v0.x * v0.x + v0.y * v0.y + v0.z * v0.z + v0.w * v0.w +
             v1.x * v1.x + v1.y * v1.y + v1.z * v1.z + v1.w * v1.w;
  s = blockSum(s);
  ss = blockSum(ss);
  float mean = s * (1.f / DIMC);
  float var = ss * (1.f / DIMC) - mean * mean;
  float rstd = rsqrtf(var + 1e-6f);
  const float* sh = mod + shOff;
  const float* sc = mod + scOff;
  int c = tid * 8;
  float xv[8] = {v0.x, v0.y, v0.z, v0.w, v1.x, v1.y, v1.z, v1.w};
  u16x8 oh, ol;
#pragma unroll
  for (int e = 0; e < 8; ++e) {
    float v = (xv[e] - mean) * rstd * (1.f + sc[c + e]) + sh[c + e];
    u16 h, l;
    splitf(v, h, l);
    oh[e] = h;
    ol[e] = l;
  }
  *(u16x8*)(outh + (size_t)row * DIMC + c) = oh;
  *(u16x8*)(outl + (size_t)row * DIMC + c) = ol;
}

// ---------------- LayerNorm + adaLN modulate -> bf16 (MoE x_act) ----------------
__global__ __launch_bounds__(256) void k_ln_mod(const float* __restrict__ X, const float* __restrict__ mod,
                                                int shOff, int scOff, u16* __restrict__ out) {
  int row = blockIdx.x, tid = threadIdx.x;
  const float4* x4 = (const float4*)(X + (size_t)row * DIMC);
  float4 v0 = x4[tid * 2], v1 = x4[tid * 2 + 1];
  float s = v0.x + v0.y + v0.z + v0.w + v1.x + v1.y + v1.z + v1.w;
  float ss = v0.x * v0.x + v0.y * v0.y + v0.z * v0.z + v0.w * v0.w +
             v1.x * v1.x + v1.y * v1.y + v1.z * v1.z + v1.w * v1.w;
  s = blockSum(s);
  ss = blockSum(ss);
  float mean = s * (1.f / DIMC);
  float var = ss * (1.f / DIMC) - mean * mean;
  float rstd = rsqrtf(var + 1e-6f);
  const float* sh = mod + shOff;
  const float* sc = mod + scOff;
  int c = tid * 8;
  float xv[8] = {v0.x, v0.y, v0.z, v0.w, v1.x, v1.y, v1.z, v1.w};
  u16x8 o;
#pragma unroll
  for (int e = 0; e < 8; ++e) o[e] = f2bf((xv[e] - mean) * rstd * (1.f + sc[c + e]) + sh[c + e]);
  *(u16x8*)(out + (size_t)row * DIMC + c) = o;
}

// ---------------- RMSNorm (strided f32 in) -> split hi/lo bf16 out, * weight * scale ----------------
__global__ __launch_bounds__(256) void k_rms_split(const float* __restrict__ X, int ldin,
                                                   const float* __restrict__ w, float scale,
                                                   u16* __restrict__ outh, u16* __restrict__ outl) {
  int row = blockIdx.x, tid = threadIdx.x;
  const float4* x4 = (const float4*)(X + (size_t)row * ldin);
  float4 v0 = x4[tid * 2], v1 = x4[tid * 2 + 1];
  float ss = v0.x * v0.x + v0.y * v0.y + v0.z * v0.z + v0.w * v0.w +
             v1.x * v1.x + v1.y * v1.y + v1.z * v1.z + v1.w * v1.w;
  ss = blockSum(ss);
  float rstd = rsqrtf(ss * (1.f / DIMC) + 1e-5f) * scale;
  int c = tid * 8;
  float xv[8] = {v0.x, v0.y, v0.z, v0.w, v1.x, v1.y, v1.z, v1.w};
  u16x8 oh, ol;
#pragma unroll
  for (int e = 0; e < 8; ++e) {
    float v = xv[e] * rstd * w[c + e];
    u16 h, l;
    splitf(v, h, l);
    oh[e] = h;
    ol[e] = l;
  }
  *(u16x8*)(outh + (size_t)row * DIMC + c) = oh;
  *(u16x8*)(outl + (size_t)row * DIMC + c) = ol;
}

// ---------------- gating: recompute LN+mod in f32, softmax over 4, top-2 -> comb[n][4] ----------------
__global__ __launch_bounds__(256) void k_gate(const float* __restrict__ img, const float* __restrict__ mod,
                                              const float* __restrict__ gw, float* __restrict__ comb) {
  int n = blockIdx.x, tid = threadIdx.x;
  const float4* x4 = (const float4*)(img + (size_t)n * DIMC);
  float4 v0 = x4[tid * 2], v1 = x4[tid * 2 + 1];
  float s = v0.x + v0.y + v0.z + v0.w + v1.x + v1.y + v1.z + v1.w;
  float ss = v0.x * v0.x + v0.y * v0.y + v0.z * v0.z + v0.w * v0.w +
             v1.x * v1.x + v1.y * v1.y + v1.z * v1.z + v1.w * v1.w;
  s = blockSum(s);
  ss = blockSum(ss);
  float mean = s * (1.f / DIMC);
  float var = ss * (1.f / DIMC) - mean * mean;
  float rstd = rsqrtf(var + 1e-6f);
  const float* sh = mod + 3 * DIMC;
  const float* sc = mod + 4 * DIMC;
  int c = tid * 8;
  float xv[8] = {v0.x, v0.y, v0.z, v0.w, v1.x, v1.y, v1.z, v1.w};
  float y[8];
#pragma unroll
  for (int e = 0; e < 8; ++e) y[e] = (xv[e] - mean) * rstd * (1.f + sc[c + e]) + sh[c + e];
  float accs[NEXP];
#pragma unroll
  for (int ex = 0; ex < NEXP; ++ex) {
    float a = 0.f;
#pragma unroll
    for (int e = 0; e < 8; ++e) a += y[e] * gw[(size_t)ex * DIMC + c + e];
    accs[ex] = blockSum(a);
  }
  if (tid == 0) {
    float mx = fmaxf(fmaxf(accs[0], accs[1]), fmaxf(accs[2], accs[3]));
    float ex0 = __expf(accs[0] - mx), ex1 = __expf(accs[1] - mx);
    float ex2 = __expf(accs[2] - mx), ex3 = __expf(accs[3] - mx);
    float inv = 1.f / (ex0 + ex1 + ex2 + ex3);
    float v[4] = {ex0 * inv, ex1 * inv, ex2 * inv, ex3 * inv};
    int i1 = 0;
    for (int e = 1; e < 4; ++e)
      if (v[e] > v[i1]) i1 = e;
    int i2 = -1;
    for (int e = 0; e < 4; ++e) {
      if (e == i1) continue;
      if (i2 < 0 || v[e] > v[i2]) i2 = e;
    }
    for (int e = 0; e < 4; ++e) comb[(size_t)n * 4 + e] = (e == i1 || e == i2) ? v[e] : 0.f;
  }
}

// ---------------- routing: deterministic per-expert token lists ----------------
__global__ __launch_bounds__(256) void k_route(const float* __restrict__ comb, int* __restrict__ gidx,
                                               float* __restrict__ cw, int* __restrict__ Mpad) {
  int wid = threadIdx.x >> 6, lane = threadIdx.x & 63;
  int base = 0;
  for (int c = 0; c < SEQ; c += 64) {
    int n = c + lane;
    float w = comb[(size_t)n * NEXP + wid];
    bool sel = w > 0.f;
    unsigned long long mask = __ballot(sel);
    int pos = __popcll(mask & ((1ull << lane) - 1ull));
    if (sel) {
      gidx[wid * RSTRIDE + base + pos] = n;
      cw[wid * RSTRIDE + base + pos] = w;
    }
    base += __popcll(mask);
  }
  int padded = (base + 127) & ~127;
  for (int i = base + lane; i < padded; i += 64) {
    gidx[wid * RSTRIDE + i] = -1;
    cw[wid * RSTRIDE + i] = 0.f;
  }
  if (lane == 0) Mpad[wid] = padded;
}

// ---------------- dense bf16 GEMM (down-proj shared): BK=64 pipelined dbuf; Cf = acc ----------------
__global__ __launch_bounds__(256, 2) void k_gemmD(const u16* __restrict__ A, const u16* __restrict__ BT,
                                                  int M, int N, int K, float* __restrict__ Cf) {
  int bx, by, bzz;
  xcd_swz(bx, by, bzz);
  __shared__ __align__(16) u16 As[2][8192], Bs[2][8192];
  const int tid = threadIdx.x, wid = tid >> 6, lane = tid & 63;
  const int l16 = lane & 15, g = lane >> 4;
  const int wr = wid >> 1, wc = wid & 1;
  const int m0 = by * 128, n0 = bx * 128;
  const int srow = lane >> 2, scol = (lane & 3) * 8;
  const u16* aS0 = A + (size_t)(m0 + wid * 32 + srow) * K + scol;
  const u16* aS1 = aS0 + (size_t)16 * K;
  const u16* bS0 = BT + (size_t)(n0 + wid * 32 + srow) * K + scol;
  const u16* bS1 = bS0 + (size_t)16 * K;

  const f32x4 zero4 = {0.f, 0.f, 0.f, 0.f};
  f32x4 acc[4][4];
#pragma unroll
  for (int mi = 0; mi < 4; ++mi)
#pragma unroll
    for (int ni = 0; ni < 4; ++ni) acc[mi][ni] = zero4;

  auto stage = [&](int b, int k0) {
    gload16(aS0 + k0, &As[b][wid * 1024]);
    gload16(aS1 + k0, &As[b][wid * 1024 + 512]);
    gload16(aS0 + k0 + 32, &As[b][4096 + wid * 1024]);
    gload16(aS1 + k0 + 32, &As[b][4096 + wid * 1024 + 512]);
    gload16(bS0 + k0, &Bs[b][wid * 1024]);
    gload16(bS1 + k0, &Bs[b][wid * 1024 + 512]);
    gload16(bS0 + k0 + 32, &Bs[b][4096 + wid * 1024]);
    gload16(bS1 + k0 + 32, &Bs[b][4096 + wid * 1024 + 512]);
  };
  auto compute = [&](int b) {
#pragma unroll
    for (int hh = 0; hh < 2; ++hh) {
      const u16* Asrc = &As[b][hh * 4096];
      const u16* Bsrc = &Bs[b][hh * 4096];
      bf16x8 af[4], bfr[4];
#pragma unroll
      for (int mi = 0; mi < 4; ++mi)
        af[mi] = *(const bf16x8*)(&Asrc[(wr * 64 + mi * 16 + l16) * 32 + g * 8]);
#pragma unroll
      for (int ni = 0; ni < 4; ++ni)
        bfr[ni] = *(const bf16x8*)(&Bsrc[(wc * 64 + ni * 16 + l16) * 32 + g * 8]);
#pragma unroll
      for (int mi = 0; mi < 4; ++mi)
#pragma unroll
        for (int ni = 0; ni < 4; ++ni)
          acc[mi][ni] = __builtin_amdgcn_mfma_f32_16x16x32_bf16(af[mi], bfr[ni], acc[mi][ni], 0, 0, 0);
    }
  };

  stage(0, 0);
  __syncthreads();
  for (int k0 = 0; k0 < K; k0 += 128) {
    if (k0 + 64 < K) stage(1, k0 + 64);
    compute(0);
    __syncthreads();
    if (k0 + 128 < K) stage(0, k0 + 128);
    compute(1);
    __syncthreads();
  }

#pragma unroll
  for (int mi = 0; mi < 4; ++mi)
#pragma unroll
    for (int ni = 0; ni < 4; ++ni) {
      const int col = n0 + wc * 64 + ni * 16 + l16;
#pragma unroll
      for (int r = 0; r < 4; ++r) {
        const int row = m0 + wr * 64 + mi * 16 + g * 4 + r;
        Cf[(size_t)row * N + col] = acc[mi][ni][r];
      }
    }
}

// ---------------- fused up-projection: BK=32 single-buffer, 24KB LDS, 3 blocks/CU ----------------
// acc1 = A@B1^T, acc3 = A@B3^T; G = silu(rt(acc1))*acc3*cw ; rt() = bf16 roundtrip (bit-identical)
template <int GATH>
__global__ __launch_bounds__(256, 3) void k_gemmUP(const u16* __restrict__ A, const u16* __restrict__ B1T0,
                                                   const u16* __restrict__ B3T0, size_t bzs, int N, int K,
                                                   const int* __restrict__ gidx0,
                                                   const float* __restrict__ cw0,
                                                   const int* __restrict__ Mp0, u16* __restrict__ G0,
                                                   size_t cz) {
  int bx, by, bz;
  xcd_swz(bx, by, bz);
  const int z = bz;
  const int m0 = by * 128;
  const int* gidxE = nullptr;
  const float* cwE = nullptr;
  if constexpr (GATH) {
    if (m0 >= Mp0[z]) return;  // by-fastest swizzle spreads early-exits over all XCDs
    gidxE = gidx0 + (size_t)z * RSTRIDE;
    cwE = cw0 + (size_t)z * RSTRIDE;
  }
  const u16* B1T = B1T0 + (size_t)z * bzs;
  const u16* B3T = B3T0 + (size_t)z * bzs;
  u16* G = G0 + (size_t)z * cz;

  __shared__ __align__(16) u16 As[4096], B1s[4096], B3s[4096];  // 24KB, BK=32
  const int tid = threadIdx.x, wid = tid >> 6, lane = tid & 63;
  const int l16 = lane & 15, g = lane >> 4;
  const int wr = wid >> 1, wc = wid & 1;
  const int n0 = bx * 128;
  const int srow = lane >> 2, scol = (lane & 3) * 8;
  const int slot0 = m0 + wid * 32 + srow;
  int row0, row1;
  if constexpr (GATH) {
    int t0 = gidxE[slot0], t1 = gidxE[slot0 + 16];
    row0 = t0 < 0 ? 0 : t0;  // pad slots read token 0; killed by cw=0
    row1 = t1 < 0 ? 0 : t1;
  } else {
    row0 = slot0;
    row1 = slot0 + 16;
  }
  const u16* aS0 = A + (size_t)row0 * K + scol;
  const u16* aS1 = A + (size_t)row1 * K + scol;
  const u16* b1S0 = B1T + (size_t)(n0 + wid * 32 + srow) * K + scol;
  const u16* b1S1 = b1S0 + (size_t)16 * K;
  const u16* b3S0 = B3T + (size_t)(n0 + wid * 32 + srow) * K + scol;
  const u16* b3S1 = b3S0 + (size_t)16 * K;

  const f32x4 zero4 = {0.f, 0.f, 0.f, 0.f};
  f32x4 acc1[4][4], acc3[4][4];
#pragma unroll
  for (int mi = 0; mi < 4; ++mi)
#pragma unroll
    for (int ni = 0; ni < 4; ++ni) {
      acc1[mi][ni] = zero4;
      acc3[mi][ni] = zero4;
    }

  for (int k0 = 0; k0 < K; k0 += 32) {
    __syncthreads();
    gload16(aS0 + k0, &As[wid * 1024]);
    gload16(aS1 + k0, &As[wid * 1024 + 512]);
    gload16(b1S0 + k0, &B1s[wid * 1024]);
    gload16(b1S1 + k0, &B1s[wid * 1024 + 512]);
    gload16(b3S0 + k0, &B3s[wid * 1024]);
    gload16(b3S1 + k0, &B3s[wid * 1024 + 512]);
    __syncthreads();
    bf16x8 af[4], b1f[4], b3f[4];
#pragma unroll
    for (int mi = 0; mi < 4; ++mi)
      af[mi] = *(const bf16x8*)(&As[(wr * 64 + mi * 16 + l16) * 32 + g * 8]);
#pragma unroll
    for (int ni = 0; ni < 4; ++ni) {
      b1f[ni] = *(const bf16x8*)(&B1s[(wc * 64 + ni * 16 + l16) * 32 + g * 8]);
      b3f[ni] = *(const bf16x8*)(&B3s[(wc * 64 + ni * 16 + l16) * 32 + g * 8]);
    }
#pragma unroll
    for (int mi = 0; mi < 4; ++mi)
#pragma unroll
      for (int ni = 0; ni < 4; ++ni) {
        acc1[mi][ni] = __builtin_amdgcn_mfma_f32_16x16x32_bf16(af[mi], b1f[ni], acc1[mi][ni], 0, 0, 0);
        acc3[mi][ni] = __builtin_amdgcn_mfma_f32_16x16x32_bf16(af[mi], b3f[ni], acc3[mi][ni], 0, 0, 0);
      }
  }

#pragma unroll
  for (int mi = 0; mi < 4; ++mi)
#pragma unroll
    for (int ni = 0; ni < 4; ++ni) {
      const int col = n0 + wc * 64 + ni * 16 + l16;
#pragma unroll
      for (int r = 0; r < 4; ++r) {
        const int slot = m0 + wr * 64 + mi * 16 + g * 4 + r;
        float hv = bf2f(f2bf(acc1[mi][ni][r]));  // emulate H1 bf16 roundtrip (bit-identical)
        float sw = hv * sigf(hv);
        float val = sw * acc3[mi][ni][r];
        if constexpr (GATH) val = val * cwE[slot];
        G[(size_t)slot * N + col] = f2bf(val);
      }
    }
}

// ---------------- routed down-projection, z-batched: ffz[z][t] += G@B2^T ----------------
__global__ __launch_bounds__(256, 2) void k_gemmR2(const u16* __restrict__ A0, size_t az,
                                                   const u16* __restrict__ BT0, size_t bzs, int N, int K,
                                                   const int* __restrict__ gidx0,
                                                   const int* __restrict__ Mp0, float* __restrict__ ffA,
                                                   float* __restrict__ ffB) {
  int bx, by, bz;
  xcd_swz(bx, by, bz);
  const int z = bz;
  const int m0 = by * 128;
  if (m0 >= Mp0[z]) return;
  const int* gidxE = gidx0 + (size_t)z * RSTRIDE;
  const u16* A = A0 + (size_t)z * az;
  const u16* BT = BT0 + (size_t)z * bzs;
  float* ff = z ? ffB : ffA;

  __shared__ __align__(16) u16 As[2][8192], Bs[2][8192];
  const int tid = threadIdx.x, wid = tid >> 6, lane = tid & 63;
  const int l16 = lane & 15, g = lane >> 4;
  const int wr = wid >> 1, wc = wid & 1;
  const int n0 = bx * 128;
  const int srow = lane >> 2, scol = (lane & 3) * 8;
  const int slot0 = m0 + wid * 32 + srow;
  const u16* aS0 = A + (size_t)slot0 * K + scol;
  const u16* aS1 = A + (size_t)(slot0 + 16) * K + scol;
  const u16* bS0 = BT + (size_t)(n0 + wid * 32 + srow) * K + scol;
  const u16* bS1 = bS0 + (size_t)16 * K;

  const f32x4 zero4 = {0.f, 0.f, 0.f, 0.f};
  f32x4 acc[4][4];
#pragma unroll
  for (int mi = 0; mi < 4; ++mi)
#pragma unroll
    for (int ni = 0; ni < 4; ++ni) acc[mi][ni] = zero4;

  auto stage = [&](int b, int k0) {
    gload16(aS0 + k0, &As[b][wid * 1024]);
    gload16(aS1 + k0, &As[b][wid * 1024 + 512]);
    gload16(aS0 + k0 + 32, &As[b][4096 + wid * 1024]);
    gload16(aS1 + k0 + 32, &As[b][4096 + wid * 1024 + 512]);
    gload16(bS0 + k0, &Bs[b][wid * 1024]);
    gload16(bS1 + k0, &Bs[b][wid * 1024 + 512]);
    gload16(bS0 + k0 + 32, &Bs[b][4096 + wid * 1024]);
    gload16(bS1 + k0 + 32, &Bs[b][4096 + wid * 1024 + 512]);
  };
  auto compute = [&](int b) {
#pragma unroll
    for (int hh = 0; hh < 2; ++hh) {
      const u16* Asrc = &As[b][hh * 4096];
      const u16* Bsrc = &Bs[b][hh * 4096];
      bf16x8 af[4], bfr[4];
#pragma unroll
      for (int mi = 0; mi < 4; ++mi)
        af[mi] = *(const bf16x8*)(&Asrc[(wr * 64 + mi * 16 + l16) * 32 + g * 8]);
#pragma unroll
      for (int ni = 0; ni < 4; ++ni)
        bfr[ni] = *(const bf16x8*)(&Bsrc[(wc * 64 + ni * 16 + l16) * 32 + g * 8]);
#pragma unroll
      for (int mi = 0; mi < 4; ++mi)
#pragma unroll
        for (int ni = 0; ni < 4; ++ni)
          acc[mi][ni] = __builtin_amdgcn_mfma_f32_16x16x32_bf16(af[mi], bfr[ni], acc[mi][ni], 0, 0, 0);
    }
  };

  stage(0, 0);
  __syncthreads();
  for (int k0 = 0; k0 < K; k0 += 128) {
    if (k0 + 64 < K) stage(1, k0 + 64);
    compute(0);
    __syncthreads();
    if (k0 + 128 < K) stage(0, k0 + 128);
    compute(1);
    __syncthreads();
  }

#pragma unroll
  for (int mi = 0; mi < 4; ++mi)
#pragma unroll
    for (int ni = 0; ni < 4; ++ni) {
      const int col = n0 + wc * 64 + ni * 16 + l16;
#pragma unroll
      for (int r = 0; r < 4; ++r) {
        const int slot = m0 + wr * 64 + mi * 16 + g * 4 + r;
        int t = gidxE[slot];
        if (t >= 0) ff[(size_t)t * N + col] += acc[mi][ni][r];
      }
    }
}

// ---------------- split-precision GEMM: pre-split hi/lo globals; pipelined dbuf ----------------
// MODE 7: Cf = acc + segmented bias (QKV fused, N=3*DIMC)
// MODE 2: Cf = (acc+bias0)*gvec[col] + resid
template <int MODE>
__global__ __launch_bounds__(256, 2) void k_gemm3s(const u16* __restrict__ Ahg, const u16* __restrict__ Alg,
                                                   const u16* __restrict__ Bhg, const u16* __restrict__ Blg,
                                                   int M, int N, int K, float* __restrict__ Cf,
                                                   const float* __restrict__ bias0,
                                                   const float* __restrict__ bias1,
                                                   const float* __restrict__ bias2,
                                                   const float* __restrict__ gvec,
                                                   const float* __restrict__ resid) {
  int bxs, bys, bzs2;
  xcd_swz(bxs, bys, bzs2);
  __shared__ __align__(16) u16 Ahs[2][4096], Als[2][4096], Bhs[2][4096], Bls[2][4096];
  const int tid = threadIdx.x, wid = tid >> 6, lane = tid & 63;
  const int l16 = lane & 15, g = lane >> 4;
  const int wr = wid >> 1, wc = wid & 1;
  const int m0 = bys * 128, n0 = bxs * 128;
  const int srow = lane >> 2, scol = (lane & 3) * 8;
  const size_t aOff0 = (size_t)(m0 + wid * 32 + srow) * K + scol;
  const size_t aOff1 = aOff0 + (size_t)16 * K;
  const size_t bOff0 = (size_t)(n0 + wid * 32 + srow) * K + scol;
  const size_t bOff1 = bOff0 + (size_t)16 * K;

  const f32x4 zero4 = {0.f, 0.f, 0.f, 0.f};
  f32x4 acc[4][4];
#pragma unroll
  for (int mi = 0; mi < 4; ++mi)
#pragma unroll
    for (int ni = 0; ni < 4; ++ni) acc[mi][ni] = zero4;

  auto stage = [&](int b, int k0) {
    gload16(Ahg + aOff0 + k0, &Ahs[b][wid * 1024]);
    gload16(Ahg + aOff1 + k0, &Ahs[b][wid * 1024 + 512]);
    gload16(Alg + aOff0 + k0, &Als[b][wid * 1024]);
    gload16(Alg + aOff1 + k0, &Als[b][wid * 1024 + 512]);
    gload16(Bhg + bOff0 + k0, &Bhs[b][wid * 1024]);
    gload16(Bhg + bOff1 + k0, &Bhs[b][wid * 1024 + 512]);
    gload16(Blg + bOff0 + k0, &Bls[b][wid * 1024]);
    gload16(Blg + bOff1 + k0, &Bls[b][wid * 1024 + 512]);
  };
  auto compute = [&](int b) {
    bf16x8 bhf[4], blf[4];
#pragma unroll
    for (int ni = 0; ni < 4; ++ni) {
      bhf[ni] = *(const bf16x8*)(&Bhs[b][(wc * 64 + ni * 16 + l16) * 32 + g * 8]);
      blf[ni] = *(const bf16x8*)(&Bls[b][(wc * 64 + ni * 16 + l16) * 32 + g * 8]);
    }
#pragma unroll
    for (int mi = 0; mi < 4; ++mi) {
      bf16x8 ahf = *(const bf16x8*)(&Ahs[b][(wr * 64 + mi * 16 + l16) * 32 + g * 8]);
      bf16x8 alf = *(const bf16x8*)(&Als[b][(wr * 64 + mi * 16 + l16) * 32 + g * 8]);
#pragma unroll
      for (int ni = 0; ni < 4; ++ni) {
        acc[mi][ni] = __builtin_amdgcn_mfma_f32_16x16x32_bf16(alf, bhf[ni], acc[mi][ni], 0, 0, 0);
        acc[mi][ni] = __builtin_amdgcn_mfma_f32_16x16x32_bf16(ahf, blf[ni], acc[mi][ni], 0, 0, 0);
        acc[mi][ni] = __builtin_amdgcn_mfma_f32_16x16x32_bf16(ahf, bhf[ni], acc[mi][ni], 0, 0, 0);
      }
    }
  };

  stage(0, 0);
  __syncthreads();
  for (int k0 = 0; k0 < K; k0 += 64) {
    if (k0 + 32 < K) stage(1, k0 + 32);
    compute(0);
    __syncthreads();
    if (k0 + 64 < K) stage(0, k0 + 64);
    compute(1);
    __syncthreads();
  }

  const float* bp = bias0;
  if constexpr (MODE == 7) bp = (n0 < DIMC) ? bias0 : (n0 < 2 * DIMC ? bias1 : bias2);
#pragma unroll
  for (int mi = 0; mi < 4; ++mi)
#pragma unroll
    for (int ni = 0; ni < 4; ++ni) {
      const int col = n0 + wc * 64 + ni * 16 + l16;
      float bv = bp ? bp[col & (DIMC - 1)] : 0.f;
#pragma unroll
      for (int r = 0; r < 4; ++r) {
        const int row = m0 + wr * 64 + mi * 16 + g * 4 + r;
        float v = acc[mi][ni][r] + bv;
        if constexpr (MODE == 7) {
          Cf[(size_t)row * N + col] = v;
        } else {
          Cf[(size_t)row * N + col] = v * gvec[col] + resid[(size_t)row * N + col];
        }
      }
    }
}

// ---------------- flash attention: head->XCD pinned (bid%8 == head%8); pre-split K/V globals ----------------
__global__ __launch_bounds__(256, 3) void k_flash3(const u16* __restrict__ qh_g, const u16* __restrict__ ql_g,
                                                   const u16* __restrict__ kh_g, const u16* __restrict__ kl_g,
                                                   const u16* __restrict__ vth_g, const u16* __restrict__ vtl_g,
                                                   u16* __restrict__ oh_g, u16* __restrict__ ol_g) {
  __shared__ __align__(16) u16 Kh[4096], Kl[4096], Vh[128 * 40], Vl[128 * 40];
  __shared__ __align__(16) u16 Pah[4][16 * 40], Pal[4][16 * 40];
  const int tid = threadIdx.x, wid = tid >> 6, lane = tid & 63;
  const int l16 = lane & 15, g = lane >> 4;
  const int bid = blockIdx.x;
  const int h = (bid & 7) + ((bid >> 8) << 3);
  const int qb = (bid >> 3) & 31;
  const int r0 = qb * 64 + wid * 16;
  const size_t hOff = (size_t)h * HDIM;

  bf16x8 qfh[4], qfl[4];
#pragma unroll
  for (int kc = 0; kc < 4; ++kc) {
    const size_t qo = (size_t)(r0 + l16) * DIMC + hOff + kc * 32 + g * 8;
    qfh[kc] = *(const bf16x8*)(qh_g + qo);
    qfl[kc] = *(const bf16x8*)(ql_g + qo);
  }

  const int kr = tid >> 3, ke0 = (tid & 7) * 16;
  const int kswz = (kr & 7) << 4;
  const int kc0 = (ke0 * 2) ^ kswz, kc1 = (ke0 * 2 + 16) ^ kswz;
  char* khp = (char*)Kh + kr * 256;
  char* klp = (char*)Kl + kr * 256;
  const size_t kOff = (size_t)kr * DIMC + hOff + ke0;
  const int vr = tid >> 1, ve0 = (tid & 1) * 16;
  char* vhp = (char*)Vh + vr * 80 + ve0 * 2;
  char* vlp = (char*)Vl + vr * 80 + ve0 * 2;
  const size_t vOff = (size_t)(hOff + vr) * SEQ + ve0;

  u16x8 kH0, kH1, kL0, kL1, vH0, vH1, vL0, vL1;
  kH0 = *(const u16x8*)(kh_g + kOff);
  kH1 = *(const u16x8*)(kh_g + kOff + 8);
  kL0 = *(const u16x8*)(kl_g + kOff);
  kL1 = *(const u16x8*)(kl_g + kOff + 8);
  vH0 = *(const u16x8*)(vth_g + vOff);
  vH1 = *(const u16x8*)(vth_g + vOff + 8);
  vL0 = *(const u16x8*)(vtl_g + vOff);
  vL1 = *(const u16x8*)(vtl_g + vOff + 8);

  const f32x4 zero4 = {0.f, 0.f, 0.f, 0.f};
  f32x4 oacc[8];
#pragma unroll
  for (int db = 0; db < 8; ++db) oacc[db] = zero4;
  float mr[4], lr[4];
#pragma unroll
  for (int r = 0; r < 4; ++r) {
    mr[r] = -3.0e38f;
    lr[r] = 0.f;
  }

  for (int j0 = 0; j0 < SEQ; j0 += 32) {
    __syncthreads();
    *(u16x8*)(khp + kc0) = kH0;
    *(u16x8*)(khp + kc1) = kH1;
    *(u16x8*)(klp + kc0) = kL0;
    *(u16x8*)(klp + kc1) = kL1;
    *(u16x8*)(vhp) = vH0;
    *(u16x8*)(vhp + 16) = vH1;
    *(u16x8*)(vlp) = vL0;
    *(u16x8*)(vlp + 16) = vL1;
    __syncthreads();
    if (j0 + 32 < SEQ) {
      const size_t ko = kOff + (size_t)(j0 + 32) * DIMC;
      const size_t vo = vOff + j0 + 32;
      kH0 = *(const u16x8*)(kh_g + ko);
      kH1 = *(const u16x8*)(kh_g + ko + 8);
      kL0 = *(const u16x8*)(kl_g + ko);
      kL1 = *(const u16x8*)(kl_g + ko + 8);
      vH0 = *(const u16x8*)(vth_g + vo);
      vH1 = *(const u16x8*)(vth_g + vo + 8);
      vL0 = *(const u16x8*)(vtl_g + vo);
      vL1 = *(const u16x8*)(vtl_g + vo + 8);
    }
    f32x4 s0 = zero4, s1 = zero4;
    __builtin_amdgcn_s_setprio(1);
#pragma unroll
    for (int kc = 0; kc < 4; ++kc) {
      const int cb = (kc * 64 + g * 16) ^ ((l16 & 7) << 4);
      bf16x8 kh0 = *(const bf16x8*)((char*)Kh + l16 * 256 + cb);
      bf16x8 kl0 = *(const bf16x8*)((char*)Kl + l16 * 256 + cb);
      bf16x8 kh1 = *(const bf16x8*)((char*)Kh + (16 + l16) * 256 + cb);
      bf16x8 kl1 = *(const bf16x8*)((char*)Kl + (16 + l16) * 256 + cb);
      s0 = __builtin_amdgcn_mfma_f32_16x16x32_bf16(qfl[kc], kh0, s0, 0, 0, 0);
      s0 = __builtin_amdgcn_mfma_f32_16x16x32_bf16(qfh[kc], kl0, s0, 0, 0, 0);
      s0 = __builtin_amdgcn_mfma_f32_16x16x32_bf16(qfh[kc], kh0, s0, 0, 0, 0);
      s1 = __builtin_amdgcn_mfma_f32_16x16x32_bf16(qfl[kc], kh1, s1, 0, 0, 0);
      s1 = __builtin_amdgcn_mfma_f32_16x16x32_bf16(qfh[kc], kl1, s1, 0, 0, 0);
      s1 = __builtin_amdgcn_mfma_f32_16x16x32_bf16(qfh[kc], kh1, s1, 0, 0, 0);
    }
    __builtin_amdgcn_s_setprio(0);
    float corr[4];
#pragma unroll
    for (int r = 0; r < 4; ++r) {
      float tm = fmaxf(s0[r], s1[r]);
#pragma unroll
      for (int m = 1; m < 16; m <<= 1) tm = fmaxf(tm, __shfl_xor(tm, m));
      float mn = fmaxf(mr[r], tm);
      corr[r] = __expf(mr[r] - mn);
      mr[r] = mn;
      float p0 = __expf(s0[r] - mn);
      float p1 = __expf(s1[r] - mn);
      lr[r] = lr[r] * corr[r] + p0 + p1;
      u16 p0h = f2bf(p0), p1h = f2bf(p1);
      Pah[wid][(g * 4 + r) * 40 + l16] = p0h;
      Pah[wid][(g * 4 + r) * 40 + 16 + l16] = p1h;
      Pal[wid][(g * 4 + r) * 40 + l16] = f2bf(p0 - bf2f(p0h));
      Pal[wid][(g * 4 + r) * 40 + 16 + l16] = f2bf(p1 - bf2f(p1h));
    }
#pragma unroll
    for (int db = 0; db < 8; ++db)
#pragma unroll
      for (int r = 0; r < 4; ++r) oacc[db][r] *= corr[r];
    bf16x8 pfh = *(const bf16x8*)(&Pah[wid][l16 * 40 + g * 8]);
    bf16x8 pfl = *(const bf16x8*)(&Pal[wid][l16 * 40 + g * 8]);
    __builtin_amdgcn_s_setprio(1);
#pragma unroll
    for (int db = 0; db < 8; ++db) {
      const int row = db * 16 + l16;
      bf16x8 vh = *(const bf16x8*)((char*)Vh + row * 80 + g * 16);
      bf16x8 vl = *(const bf16x8*)((char*)Vl + row * 80 + g * 16);
      oacc[db] = __builtin_amdgcn_mfma_f32_16x16x32_bf16(pfl, vh, oacc[db], 0, 0, 0);
      oacc[db] = __builtin_amdgcn_mfma_f32_16x16x32_bf16(pfh, vl, oacc[db], 0, 0, 0);
      oacc[db] = __builtin_amdgcn_mfma_f32_16x16x32_bf16(pfh, vh, oacc[db], 0, 0, 0);
    }
    __builtin_amdgcn_s_setprio(0);
  }
#pragma unroll
  for (int r = 0; r < 4; ++r) {
#pragma unroll
    for (int m = 1; m < 16; m <<= 1) lr[r] += __shfl_xor(lr[r], m);
    lr[r] = 1.f / lr[r];
  }
#pragma unroll
  for (int db = 0; db < 8; ++db)
#pragma unroll
    for (int r = 0; r < 4; ++r) {
      float v = oacc[db][r] * lr[r];
      u16 hh, ll;
      splitf(v, hh, ll);
      const size_t idx = (size_t)(r0 + g * 4 + r) * DIMC + hOff + db * 16 + l16;
      oh_g[idx] = hh;
      ol_g[idx] = ll;
    }
}

// ---------------- final: out = g_mlp[col]*(ffA+ffB) + img   (img aliases out; in-place) ----------------
__global__ __launch_bounds__(256) void k_final(const float* __restrict__ ffA, const float* __restrict__ ffB,
                                               const float* img, const float* __restrict__ mod,
                                               float* out) {
  const float4* gm = (const float4*)(mod + 5 * DIMC);
  const int total = SEQ * DIMC / 4;
  const int stride = gridDim.x * blockDim.x;
  for (int i = blockIdx.x * blockDim.x + threadIdx.x; i < total; i += stride) {
    int col4 = i & (DIMC / 4 - 1);
    float4 gv = gm[col4];
    float4 fa = ((const float4*)ffA)[i];
    float4 fb = ((const float4*)ffB)[i];
    float4 iv = ((const float4*)img)[i];
    float4 ov;
    ov.x = gv.x * (fa.x + fb.x) + iv.x;
    ov.y = gv.y * (fa.y + fb.y) + iv.y;
    ov.z = gv.z * (fa.z + fb.z) + iv.z;
    ov.w = gv.w * (fa.w + fb.w) + iv.w;
    ((float4*)out)[i] = ov;
  }
}

extern "C" void kernel_launch(void* const* d_in, const int* in_sizes, int n_in, void* d_out, int out_size,
                              void* d_ws, size_t ws_size, hipStream_t stream) {
  (void)in_sizes; (void)n_in; (void)out_size; (void)ws_size;
  const float* image_tokens = (const float*)d_in[0];
  const float* adaln_input = (const float*)d_in[1];
  const float* W_ada = (const float*)d_in[2];
  const float* b_ada = (const float*)d_in[3];
  const float* Wq = (const float*)d_in[4];
  const float* bq = (const float*)d_in[5];
  const float* Wk = (const float*)d_in[6];
  const float* bk = (const float*)d_in[7];
  const float* Wv = (const float*)d_in[8];
  const float* bv = (const float*)d_in[9];
  const float* q_rms_w = (const float*)d_in[10];
  const float* k_rms_w = (const float*)d_in[11];
  const float* Wo = (const float*)d_in[12];
  const float* bo = (const float*)d_in[13];
  const float* gate_w = (const float*)d_in[14];
  const float* We1 = (const float*)d_in[15];
  const float* We3 = (const float*)d_in[16];
  const float* We2 = (const float*)d_in[17];
  const float* Ws1 = (const float*)d_in[18];
  const float* Ws3 = (const float*)d_in[19];
  const float* Ws2 = (const float*)d_in[20];

  // ---- workspace: ~229 MB; attention region aliased by MoE phase ----
  char* cur = (char*)d_ws;
  auto alloc = [&](size_t n) {
    char* p = cur;
    cur += (n + 255) & ~(size_t)255;
    return p;
  };
  float* modv = (float*)alloc((size_t)MOD6 * 4);
  float* adap = (float*)alloc((size_t)16 * MOD6 * 4);
  float* comb = (float*)alloc((size_t)SEQ * NEXP * 4);
  int* gidx = (int*)alloc((size_t)NEXP * RSTRIDE * 4);
  float* cw = (float*)alloc((size_t)NEXP * RSTRIDE * 4);
  int* Mpad = (int*)alloc((size_t)NEXP * 4);
  // attention region start (~184.6MB contiguous):
  u16* xh = (u16*)alloc((size_t)SEQ * DIMC * 2);
  u16* xl = (u16*)alloc((size_t)SEQ * DIMC * 2);
  u16* wTh3 = (u16*)alloc((size_t)3 * DIMC * DIMC * 2);
  u16* wTl3 = (u16*)alloc((size_t)3 * DIMC * DIMC * 2);
  float* tf3 = (float*)alloc((size_t)SEQ * 3 * DIMC * 4);
  u16* qhb = (u16*)alloc((size_t)SEQ * DIMC * 2);
  u16* qlb = (u16*)alloc((size_t)SEQ * DIMC * 2);
  u16* khb = (u16*)alloc((size_t)SEQ * DIMC * 2);
  u16* klb = (u16*)alloc((size_t)SEQ * DIMC * 2);
  u16* vth = (u16*)alloc((size_t)SEQ * DIMC * 2);
  u16* vtl = (u16*)alloc((size_t)SEQ * DIMC * 2);
  u16* aoh = (u16*)alloc((size_t)SEQ * DIMC * 2);
  u16* aol = (u16*)alloc((size_t)SEQ * DIMC * 2);
  // end attention region
  u16* x_act = (u16*)alloc((size_t)SEQ * DIMC * 2);
  float* ff = (float*)alloc((size_t)SEQ * DIMC * 4);
  float* ffB = (float*)alloc((size_t)SEQ * DIMC * 4);
  float* img = (float*)d_out;  // MODE2 writes before any read
  // MoE-phase aliases into the dead attention region:
  const size_t BZ = (size_t)HIDC * DIMC;
  const size_t CZ = (size_t)RSTRIDE * HIDC;
  u16* moe0 = xh;
  u16* wbufE1 = moe0;
  u16* wbufE3 = moe0 + 2 * BZ;
  u16* G2 = moe0 + 4 * BZ;
  u16* wbufS1 = moe0;
  u16* wbufS3 = moe0 + (size_t)HSH * DIMC;
  u16* wbufS2 = moe0 + (size_t)2 * HSH * DIMC;
  u16* Gs = moe0 + (size_t)3 * HSH * DIMC;

  dim3 blk(256);

  // adaLN modulation vector
  k_adaln_p<<<dim3(MOD6 / 256, 16), blk, 0, stream>>>(adaln_input, W_ada, adap);
  k_adaln_r<<<dim3(MOD6 / 256), blk, 0, stream>>>(adap, b_ada, modv);

  // ---- attention branch (f32-accurate; QKV fused into one N=6144 GEMM) ----
  k_ln_mod_split<<<dim3(SEQ), blk, 0, stream>>>(image_tokens, modv, 0, DIMC, xh, xl);
  k_transpose_s<<<dim3(DIMC / 32, DIMC / 32), blk, 0, stream>>>(Wq, wTh3, wTl3, DIMC, DIMC, DIMC);
  k_transpose_s<<<dim3(DIMC / 32, DIMC / 32), blk, 0, stream>>>(
      Wk, wTh3 + (size_t)DIMC * DIMC, wTl3 + (size_t)DIMC * DIMC, DIMC, DIMC, DIMC);
  k_transpose_s<<<dim3(DIMC / 32, DIMC / 32), blk, 0, stream>>>(
      Wv, wTh3 + (size_t)2 * DIMC * DIMC, wTl3 + (size_t)2 * DIMC * DIMC, DIMC, DIMC, DIMC);
  k_gemm3s<7><<<dim3(3 * DIMC / 128, SEQ / 128), blk, 0, stream>>>(
      xh, xl, wTh3, wTl3, SEQ, 3 * DIMC, DIMC, tf3, bq, bk, bv, nullptr, nullptr);
  k_rms_split<<<dim3(SEQ), blk, 0, stream>>>(tf3, 3 * DIMC, q_rms_w, 0.08838834764831845f, qhb, qlb);
  k_rms_split<<<dim3(SEQ), blk, 0, stream>>>(tf3 + DIMC, 3 * DIMC, k_rms_w, 1.f, khb, klb);
  k_transpose_s<<<dim3(DIMC / 32, SEQ / 32), blk, 0, stream>>>(tf3 + 2 * DIMC, vth, vtl, SEQ, DIMC,
                                                               3 * DIMC);
  k_flash3<<<dim3(SEQ / 64 * NHEAD), blk, 0, stream>>>(qhb, qlb, khb, klb, vth, vtl, aoh, aol);
  k_transpose_s<<<dim3(DIMC / 32, DIMC / 32), blk, 0, stream>>>(Wo, wTh3, wTl3, DIMC, DIMC, DIMC);
  k_gemm3s<2><<<dim3(DIMC / 128, SEQ / 128), blk, 0, stream>>>(
      aoh, aol, wTh3, wTl3, SEQ, DIMC, DIMC, img, bo, nullptr, nullptr, modv + 2 * DIMC, image_tokens);

  // ---- MoE branch ----
  k_ln_mod<<<dim3(SEQ), blk, 0, stream>>>(img, modv, 3 * DIMC, 4 * DIMC, x_act);
  k_gate<<<dim3(SEQ), blk, 0, stream>>>(img, modv, gate_w, comb);
  k_route<<<dim3(1), blk, 0, stream>>>(comb, gidx, cw, Mpad);
  hipMemsetAsync(ffB, 0, (size_t)SEQ * DIMC * 4, stream);  // ffB accumulator for odd experts

  // shared expert (fused up-proj; down-proj initializes ff with a plain store)
  k_transpose<<<dim3(HSH / 32, DIMC / 32), blk, 0, stream>>>(Ws1, wbufS1, DIMC, HSH, HSH, 0, 0);
  k_transpose<<<dim3(HSH / 32, DIMC / 32), blk, 0, stream>>>(Ws3, wbufS3, DIMC, HSH, HSH, 0, 0);
  k_gemmUP<0><<<dim3(HSH / 128, SEQ / 128, 1), blk, 0, stream>>>(
      x_act, wbufS1, wbufS3, 0, HSH, DIMC, nullptr, nullptr, nullptr, Gs, 0);
  k_transpose<<<dim3(DIMC / 32, HSH / 32), blk, 0, stream>>>(Ws2, wbufS2, HSH, DIMC, DIMC, 0, 0);
  k_gemmD<<<dim3(DIMC / 128, SEQ / 128), blk, 0, stream>>>(Gs, wbufS2, SEQ, DIMC, HSH, ff);

  // routed experts, z-batched pairs (up-proj fused; down-proj z-batched via split ff/ffB)
  const size_t WE = (size_t)DIMC * HIDC;
  for (int p = 0; p < 2; ++p) {
    const int e0 = p * 2;
    k_transpose<<<dim3(HIDC / 32, DIMC / 32, 2), blk, 0, stream>>>(We1 + (size_t)e0 * WE, wbufE1,
                                                                   DIMC, HIDC, HIDC, WE, BZ);
    k_transpose<<<dim3(HIDC / 32, DIMC / 32, 2), blk, 0, stream>>>(We3 + (size_t)e0 * WE, wbufE3,
                                                                   DIMC, HIDC, HIDC, WE, BZ);
    k_gemmUP<1><<<dim3(HIDC / 128, SEQ / 128, 2), blk, 0, stream>>>(
        x_act, wbufE1, wbufE3, BZ, HIDC, DIMC, gidx + e0 * RSTRIDE, cw + e0 * RSTRIDE, Mpad + e0, G2,
        CZ);
    k_transpose<<<dim3(DIMC / 32, HIDC / 32, 2), blk, 0, stream>>>(We2 + (size_t)e0 * WE, wbufE1,
                                                                   HIDC, DIMC, DIMC, WE, BZ);
    k_gemmR2<<<dim3(DIMC / 128, SEQ / 128, 2), blk, 0, stream>>>(
        G2, CZ, wbufE1, BZ, DIMC, HIDC, gidx + e0 * RSTRIDE, Mpad + e0, ff, ffB);
  }

  k_final<<<dim3(1024), blk, 0, stream>>>(ff, ffB, img, modv, (float*)d_out);
}

// Round 16
// 1369.540 us; speedup vs baseline: 1.5072x; 1.5072x over previous
//
#include <hip/hip_runtime.h>
#include <hip/hip_bf16.h>

typedef unsigned short u16;
typedef __bf16 bf16x8 __attribute__((ext_vector_type(8)));
typedef float f32x4 __attribute__((ext_vector_type(4)));
typedef unsigned short u16x8 __attribute__((ext_vector_type(8)));

constexpr int DIMC = 2048;
constexpr int SEQ = 2048;
constexpr int NHEAD = 16;
constexpr int HDIM = 128;
constexpr int NEXP = 4;
constexpr int HIDC = 5632;
constexpr int HSH = 2816;
constexpr int MOD6 = 6 * DIMC;
constexpr int RSTRIDE = 2304;

static __device__ __forceinline__ u16 f2bf(float f) {
  __hip_bfloat16 b = __float2bfloat16(f);
  return __builtin_bit_cast(u16, b);
}
static __device__ __forceinline__ float bf2f(u16 u) {
  unsigned int x = ((unsigned int)u) << 16;
  return __builtin_bit_cast(float, x);
}
static __device__ __forceinline__ float sigf(float x) { return 1.f / (1.f + __expf(-x)); }
static __device__ __forceinline__ void splitf(float f, u16& h, u16& l) {
  h = f2bf(f);
  l = f2bf(f - bf2f(h));
}

static __device__ __forceinline__ void gload16(const void* src, void* dst) {
  __builtin_amdgcn_global_load_lds((const __attribute__((address_space(1))) void*)src,
                                   (__attribute__((address_space(3))) void*)dst, 16, 0, 0);
}

// chunked XCD swizzle, BY-FASTEST decode (requires nwg % 8 == 0; bijective).
static __device__ __forceinline__ void xcd_swz(int& bx, int& by, int& bz) {
  const int nx = gridDim.x, ny = gridDim.y;
  const int flat = blockIdx.x + nx * (blockIdx.y + ny * blockIdx.z);
  const int nwg = nx * ny * gridDim.z;
  const int swz = (flat & 7) * (nwg >> 3) + (flat >> 3);
  by = swz % ny;
  const int t = swz / ny;
  bx = t % nx;
  bz = t / nx;
}

// block = 256 threads (4 waves); returns total across block to all threads
static __device__ __forceinline__ float blockSum(float v) {
#pragma unroll
  for (int m = 1; m < 64; m <<= 1) v += __shfl_xor(v, m);
  __shared__ float s[4];
  int w = threadIdx.x >> 6;
  if ((threadIdx.x & 63) == 0) s[w] = v;
  __syncthreads();
  float r = s[0] + s[1] + s[2] + s[3];
  __syncthreads();
  return r;
}

// ---------------- transpose f32 [R,C] (row stride ldin) -> bf16 [C,R]; z-batched ----------------
__global__ __launch_bounds__(256) void k_transpose(const float* __restrict__ in, u16* __restrict__ out,
                                                   int R, int C, int ldin, size_t inz, size_t outz) {
  __shared__ __align__(16) float tile[32][33];
  const float* inp = in + (size_t)blockIdx.z * inz;
  u16* outp = out + (size_t)blockIdx.z * outz;
  int tx = threadIdx.x & 31, ty = threadIdx.x >> 5;
  int c0 = blockIdx.x * 32, r0 = blockIdx.y * 32;
#pragma unroll
  for (int i = 0; i < 32; i += 8)
    tile[ty + i][tx] = inp[(size_t)(r0 + ty + i) * ldin + c0 + tx];
  __syncthreads();
#pragma unroll
  for (int i = 0; i < 32; i += 8)
    outp[(size_t)(c0 + ty + i) * R + r0 + tx] = f2bf(tile[tx][ty + i]);
}

// ---------------- transpose f32 [R,C] -> split bf16 hi/lo [C,R] ----------------
__global__ __launch_bounds__(256) void k_transpose_s(const float* __restrict__ in, u16* __restrict__ outh,
                                                     u16* __restrict__ outl, int R, int C, int ldin) {
  __shared__ __align__(16) float tile[32][33];
  int tx = threadIdx.x & 31, ty = threadIdx.x >> 5;
  int c0 = blockIdx.x * 32, r0 = blockIdx.y * 32;
#pragma unroll
  for (int i = 0; i < 32; i += 8)
    tile[ty + i][tx] = in[(size_t)(r0 + ty + i) * ldin + c0 + tx];
  __syncthreads();
#pragma unroll
  for (int i = 0; i < 32; i += 8) {
    float v = tile[tx][ty + i];
    u16 h, l;
    splitf(v, h, l);
    size_t idx = (size_t)(c0 + ty + i) * R + r0 + tx;
    outh[idx] = h;
    outl[idx] = l;
  }
}

// ---------------- adaLN: mod = silu(a) @ W_ada + b_ada, split over 16 d-slices ----------------
__global__ __launch_bounds__(256) void k_adaln_p(const float* __restrict__ a, const float* __restrict__ W,
                                                 float* __restrict__ partial) {
  __shared__ float sa[128];
  int tid = threadIdx.x, slice = blockIdx.y;
  if (tid < 128) { float v = a[slice * 128 + tid]; sa[tid] = v * sigf(v); }
  __syncthreads();
  int j = blockIdx.x * 256 + tid;
  float acc = 0.f;
#pragma unroll 4
  for (int d = 0; d < 128; ++d) acc += sa[d] * W[(size_t)(slice * 128 + d) * MOD6 + j];
  partial[(size_t)slice * MOD6 + j] = acc;
}
__global__ __launch_bounds__(256) void k_adaln_r(const float* __restrict__ partial, const float* __restrict__ b,
                                                 float* __restrict__ mod) {
  int j = blockIdx.x * 256 + threadIdx.x;
  float acc = b[j];
#pragma unroll
  for (int s = 0; s < 16; ++s) acc += partial[(size_t)s * MOD6 + j];
  mod[j] = acc;
}

// ---------------- LayerNorm + adaLN modulate -> split hi/lo bf16 (attention x) ----------------
__global__ __launch_bounds__(256) void k_ln_mod_split(const float* __restrict__ X, const float* __restrict__ mod,
                                                      int shOff, int scOff, u16* __restrict__ outh,
                                                      u16* __restrict__ outl) {
  int row = blockIdx.x, tid = threadIdx.x;
  const float4* x4 = (const float4*)(X + (size_t)row * DIMC);
  float4 v0 = x4[tid * 2], v1 = x4[tid * 2 + 1];
  float s = v0.x + v0.y + v0.z + v0.w + v1.x + v1.y + v1.z + v1.w;
  float ss = v0.x * v0.x + v0.y * v0.y + v0.z * v0.z + v0.w * v0.w +
             v1.x * v1.x + v1.y * v1.y + v1.z * v1.z + v1.w * v1.w;
  s = blockSum(s);
  ss = blockSum(ss);
  float mean = s * (1.f / DIMC);
  float var = ss * (1.f / DIMC) - mean * mean;
  float rstd = rsqrtf(var + 1e-6f);
  const float* sh = mod + shOff;
  const float* sc = mod + scOff;
  int c = tid * 8;
  float xv[8] = {v0.x, v0.y, v0.z, v0.w, v1.x, v1.y, v1.z, v1.w};
  u16x8 oh, ol;
#pragma unroll
  for (int e = 0; e < 8; ++e) {
    float v = (xv[e] - mean) * rstd * (1.f + sc[c + e]) + sh[c + e];
    u16 h, l;
    splitf(v, h, l);
    oh[e] = h;
    ol[e] = l;
  }
  *(u16x8*)(outh + (size_t)row * DIMC + c) = oh;
  *(u16x8*)(outl + (size_t)row * DIMC + c) = ol;
}

// ---------------- LayerNorm + adaLN modulate -> bf16 (MoE x_act) ----------------
__global__ __launch_bounds__(256) void k_ln_mod(const float* __restrict__ X, const float* __restrict__ mod,
                                                int shOff, int scOff, u16* __restrict__ out) {
  int row = blockIdx.x, tid = threadIdx.x;
  const float4* x4 = (const float4*)(X + (size_t)row * DIMC);
  float4 v0 = x4[tid * 2], v1 = x4[tid * 2 + 1];
  float s = v0.x + v0.y + v0.z + v0.w + v1.x + v1.y + v1.z + v1.w;
  float ss = v0.x * v0.x + v0.y * v0.y + v0.z * v0.z + v0.w * v0.w +
             v1.x * v1.x + v1.y * v1.y + v1.z * v1.z + v1.w * v1.w;
  s = blockSum(s);
  ss = blockSum(ss);
  float mean = s * (1.f / DIMC);
  float var = ss * (1.f / DIMC) - mean * mean;
  float rstd = rsqrtf(var + 1e-6f);
  const float* sh = mod + shOff;
  const float* sc = mod + scOff;
  int c = tid * 8;
  float xv[8] = {v0.x, v0.y, v0.z, v0.w, v1.x, v1.y, v1.z, v1.w};
  u16x8 o;
#pragma unroll
  for (int e = 0; e < 8; ++e) o[e] = f2bf((xv[e] - mean) * rstd * (1.f + sc[c + e]) + sh[c + e]);
  *(u16x8*)(out + (size_t)row * DIMC + c) = o;
}

// ---------------- RMSNorm (strided f32 in) -> split hi/lo bf16 out, * weight * scale ----------------
__global__ __launch_bounds__(256) void k_rms_split(const float* __restrict__ X, int ldin,
                                                   const float* __restrict__ w, float scale,
                                                   u16* __restrict__ outh, u16* __restrict__ outl) {
  int row = blockIdx.x, tid = threadIdx.x;
  const float4* x4 = (const float4*)(X + (size_t)row * ldin);
  float4 v0 = x4[tid * 2], v1 = x4[tid * 2 + 1];
  float ss = v0.x * v0.x + v0.y * v0.y + v0.z * v0.z + v0.w * v0.w +
             v1.x * v1.x + v1.y * v1.y + v1.z * v1.z + v1.w * v1.w;
  ss = blockSum(ss);
  float rstd = rsqrtf(ss * (1.f / DIMC) + 1e-5f) * scale;
  int c = tid * 8;
  float xv[8] = {v0.x, v0.y, v0.z, v0.w, v1.x, v1.y, v1.z, v1.w};
  u16x8 oh, ol;
#pragma unroll
  for (int e = 0; e < 8; ++e) {
    float v = xv[e] * rstd * w[c + e];
    u16 h, l;
    splitf(v, h, l);
    oh[e] = h;
    ol[e] = l;
  }
  *(u16x8*)(outh + (size_t)row * DIMC + c) = oh;
  *(u16x8*)(outl + (size_t)row * DIMC + c) = ol;
}

// ---------------- gating: recompute LN+mod in f32, softmax over 4, top-2 -> comb[n][4] ----------------
__global__ __launch_bounds__(256) void k_gate(const float* __restrict__ img, const float* __restrict__ mod,
                                              const float* __restrict__ gw, float* __restrict__ comb) {
  int n = blockIdx.x, tid = threadIdx.x;
  const float4* x4 = (const float4*)(img + (size_t)n * DIMC);
  float4 v0 = x4[tid * 2], v1 = x4[tid * 2 + 1];
  float s = v0.x + v0.y + v0.z + v0.w + v1.x + v1.y + v1.z + v1.w;
  float ss = v0.x * v0.x + v0.y * v0.y + v0.z * v0.z + v0.w * v0.w +
             v1.x * v1.x + v1.y * v1.y + v1.z * v1.z + v1.w * v1.w;
  s = blockSum(s);
  ss = blockSum(ss);
  float mean = s * (1.f / DIMC);
  float var = ss * (1.f / DIMC) - mean * mean;
  float rstd = rsqrtf(var + 1e-6f);
  const float* sh = mod + 3 * DIMC;
  const float* sc = mod + 4 * DIMC;
  int c = tid * 8;
  float xv[8] = {v0.x, v0.y, v0.z, v0.w, v1.x, v1.y, v1.z, v1.w};
  float y[8];
#pragma unroll
  for (int e = 0; e < 8; ++e) y[e] = (xv[e] - mean) * rstd * (1.f + sc[c + e]) + sh[c + e];
  float accs[NEXP];
#pragma unroll
  for (int ex = 0; ex < NEXP; ++ex) {
    float a = 0.f;
#pragma unroll
    for (int e = 0; e < 8; ++e) a += y[e] * gw[(size_t)ex * DIMC + c + e];
    accs[ex] = blockSum(a);
  }
  if (tid == 0) {
    float mx = fmaxf(fmaxf(accs[0], accs[1]), fmaxf(accs[2], accs[3]));
    float ex0 = __expf(accs[0] - mx), ex1 = __expf(accs[1] - mx);
    float ex2 = __expf(accs[2] - mx), ex3 = __expf(accs[3] - mx);
    float inv = 1.f / (ex0 + ex1 + ex2 + ex3);
    float v[4] = {ex0 * inv, ex1 * inv, ex2 * inv, ex3 * inv};
    int i1 = 0;
    for (int e = 1; e < 4; ++e)
      if (v[e] > v[i1]) i1 = e;
    int i2 = -1;
    for (int e = 0; e < 4; ++e) {
      if (e == i1) continue;
      if (i2 < 0 || v[e] > v[i2]) i2 = e;
    }
    for (int e = 0; e < 4; ++e) comb[(size_t)n * 4 + e] = (e == i1 || e == i2) ? v[e] : 0.f;
  }
}

// ---------------- routing: deterministic per-expert token lists ----------------
__global__ __launch_bounds__(256) void k_route(const float* __restrict__ comb, int* __restrict__ gidx,
                                               float* __restrict__ cw, int* __restrict__ Mpad) {
  int wid = threadIdx.x >> 6, lane = threadIdx.x & 63;
  int base = 0;
  for (int c = 0; c < SEQ; c += 64) {
    int n = c + lane;
    float w = comb[(size_t)n * NEXP + wid];
    bool sel = w > 0.f;
    unsigned long long mask = __ballot(sel);
    int pos = __popcll(mask & ((1ull << lane) - 1ull));
    if (sel) {
      gidx[wid * RSTRIDE + base + pos] = n;
      cw[wid * RSTRIDE + base + pos] = w;
    }
    base += __popcll(mask);
  }
  int padded = (base + 127) & ~127;
  for (int i = base + lane; i < padded; i += 64) {
    gidx[wid * RSTRIDE + i] = -1;
    cw[wid * RSTRIDE + i] = 0.f;
  }
  if (lane == 0) Mpad[wid] = padded;
}

// ---------------- dense bf16 GEMM (down-proj shared): BK=64 pipelined dbuf; Cf = acc ----------------
__global__ __launch_bounds__(256, 2) void k_gemmD(const u16* __restrict__ A, const u16* __restrict__ BT,
                                                  int M, int N, int K, float* __restrict__ Cf) {
  int bx, by, bzz;
  xcd_swz(bx, by, bzz);
  __shared__ __align__(16) u16 As[2][8192], Bs[2][8192];
  const int tid = threadIdx.x, wid = tid >> 6, lane = tid & 63;
  const int l16 = lane & 15, g = lane >> 4;
  const int wr = wid >> 1, wc = wid & 1;
  const int m0 = by * 128, n0 = bx * 128;
  const int srow = lane >> 2, scol = (lane & 3) * 8;
  const u16* aS0 = A + (size_t)(m0 + wid * 32 + srow) * K + scol;
  const u16* aS1 = aS0 + (size_t)16 * K;
  const u16* bS0 = BT + (size_t)(n0 + wid * 32 + srow) * K + scol;
  const u16* bS1 = bS0 + (size_t)16 * K;

  const f32x4 zero4 = {0.f, 0.f, 0.f, 0.f};
  f32x4 acc[4][4];
#pragma unroll
  for (int mi = 0; mi < 4; ++mi)
#pragma unroll
    for (int ni = 0; ni < 4; ++ni) acc[mi][ni] = zero4;

  auto stage = [&](int b, int k0) {
    gload16(aS0 + k0, &As[b][wid * 1024]);
    gload16(aS1 + k0, &As[b][wid * 1024 + 512]);
    gload16(aS0 + k0 + 32, &As[b][4096 + wid * 1024]);
    gload16(aS1 + k0 + 32, &As[b][4096 + wid * 1024 + 512]);
    gload16(bS0 + k0, &Bs[b][wid * 1024]);
    gload16(bS1 + k0, &Bs[b][wid * 1024 + 512]);
    gload16(bS0 + k0 + 32, &Bs[b][4096 + wid * 1024]);
    gload16(bS1 + k0 + 32, &Bs[b][4096 + wid * 1024 + 512]);
  };
  auto compute = [&](int b) {
#pragma unroll
    for (int hh = 0; hh < 2; ++hh) {
      const u16* Asrc = &As[b][hh * 4096];
      const u16* Bsrc = &Bs[b][hh * 4096];
      bf16x8 af[4], bfr[4];
#pragma unroll
      for (int mi = 0; mi < 4; ++mi)
        af[mi] = *(const bf16x8*)(&Asrc[(wr * 64 + mi * 16 + l16) * 32 + g * 8]);
#pragma unroll
      for (int ni = 0; ni < 4; ++ni)
        bfr[ni] = *(const bf16x8*)(&Bsrc[(wc * 64 + ni * 16 + l16) * 32 + g * 8]);
#pragma unroll
      for (int mi = 0; mi < 4; ++mi)
#pragma unroll
        for (int ni = 0; ni < 4; ++ni)
          acc[mi][ni] = __builtin_amdgcn_mfma_f32_16x16x32_bf16(af[mi], bfr[ni], acc[mi][ni], 0, 0, 0);
    }
  };

  stage(0, 0);
  __syncthreads();
  for (int k0 = 0; k0 < K; k0 += 128) {
    if (k0 + 64 < K) stage(1, k0 + 64);
    compute(0);
    __syncthreads();
    if (k0 + 128 < K) stage(0, k0 + 128);
    compute(1);
    __syncthreads();
  }

#pragma unroll
  for (int mi = 0; mi < 4; ++mi)
#pragma unroll
    for (int ni = 0; ni < 4; ++ni) {
      const int col = n0 + wc * 64 + ni * 16 + l16;
#pragma unroll
      for (int r = 0; r < 4; ++r) {
        const int row = m0 + wr * 64 + mi * 16 + g * 4 + r;
        Cf[(size_t)row * N + col] = acc[mi][ni][r];
      }
    }
}

// ---------------- fused up-projection (R12/R14 version: single-buffered BK=64, occupancy 2) ----------------
// acc1 = A@B1^T, acc3 = A@B3^T; G = silu(rt(acc1))*acc3*cw ; rt() = bf16 roundtrip (bit-identical)
// NOTE: keep __launch_bounds__(256,2) — any occupancy-3 bound spills the dual accumulators
// (R13/R15: VGPR 104->84, WRITE_SIZE 29.5MB->600-900MB, dur 180->500-590 us).
template <int GATH>
__global__ __launch_bounds__(256, 2) void k_gemmUP(const u16* __restrict__ A, const u16* __restrict__ B1T0,
                                                   const u16* __restrict__ B3T0, size_t bzs, int N, int K,
                                                   const int* __restrict__ gidx0,
                                                   const float* __restrict__ cw0,
                                                   const int* __restrict__ Mp0, u16* __restrict__ G0,
                                                   size_t cz) {
  int bx, by, bz;
  xcd_swz(bx, by, bz);
  const int z = bz;
  const int m0 = by * 128;
  const int* gidxE = nullptr;
  const float* cwE = nullptr;
  if constexpr (GATH) {
    if (m0 >= Mp0[z]) return;  // by-fastest swizzle spreads early-exits over all XCDs
    gidxE = gidx0 + (size_t)z * RSTRIDE;
    cwE = cw0 + (size_t)z * RSTRIDE;
  }
  const u16* B1T = B1T0 + (size_t)z * bzs;
  const u16* B3T = B3T0 + (size_t)z * bzs;
  u16* G = G0 + (size_t)z * cz;

  __shared__ __align__(16) u16 As[8192], B1s[8192], B3s[8192];  // 48KB, BK=64
  const int tid = threadIdx.x, wid = tid >> 6, lane = tid & 63;
  const int l16 = lane & 15, g = lane >> 4;
  const int wr = wid >> 1, wc = wid & 1;
  const int n0 = bx * 128;
  const int srow = lane >> 2, scol = (lane & 3) * 8;
  const int slot0 = m0 + wid * 32 + srow;
  int row0, row1;
  if constexpr (GATH) {
    int t0 = gidxE[slot0], t1 = gidxE[slot0 + 16];
    row0 = t0 < 0 ? 0 : t0;  // pad slots read token 0; killed by cw=0
    row1 = t1 < 0 ? 0 : t1;
  } else {
    row0 = slot0;
    row1 = slot0 + 16;
  }
  const u16* aS0 = A + (size_t)row0 * K + scol;
  const u16* aS1 = A + (size_t)row1 * K + scol;
  const u16* b1S0 = B1T + (size_t)(n0 + wid * 32 + srow) * K + scol;
  const u16* b1S1 = b1S0 + (size_t)16 * K;
  const u16* b3S0 = B3T + (size_t)(n0 + wid * 32 + srow) * K + scol;
  const u16* b3S1 = b3S0 + (size_t)16 * K;

  const f32x4 zero4 = {0.f, 0.f, 0.f, 0.f};
  f32x4 acc1[4][4], acc3[4][4];
#pragma unroll
  for (int mi = 0; mi < 4; ++mi)
#pragma unroll
    for (int ni = 0; ni < 4; ++ni) {
      acc1[mi][ni] = zero4;
      acc3[mi][ni] = zero4;
    }

  for (int k0 = 0; k0 < K; k0 += 64) {
    __syncthreads();
    gload16(aS0 + k0, &As[wid * 1024]);
    gload16(aS1 + k0, &As[wid * 1024 + 512]);
    gload16(aS0 + k0 + 32, &As[4096 + wid * 1024]);
    gload16(aS1 + k0 + 32, &As[4096 + wid * 1024 + 512]);
    gload16(b1S0 + k0, &B1s[wid * 1024]);
    gload16(b1S1 + k0, &B1s[wid * 1024 + 512]);
    gload16(b1S0 + k0 + 32, &B1s[4096 + wid * 1024]);
    gload16(b1S1 + k0 + 32, &B1s[4096 + wid * 1024 + 512]);
    gload16(b3S0 + k0, &B3s[wid * 1024]);
    gload16(b3S1 + k0, &B3s[wid * 1024 + 512]);
    gload16(b3S0 + k0 + 32, &B3s[4096 + wid * 1024]);
    gload16(b3S1 + k0 + 32, &B3s[4096 + wid * 1024 + 512]);
    __syncthreads();
#pragma unroll
    for (int hh = 0; hh < 2; ++hh) {
      const u16* Asrc = &As[hh * 4096];
      const u16* B1src = &B1s[hh * 4096];
      const u16* B3src = &B3s[hh * 4096];
      bf16x8 af[4], b1f[4], b3f[4];
#pragma unroll
      for (int mi = 0; mi < 4; ++mi)
        af[mi] = *(const bf16x8*)(&Asrc[(wr * 64 + mi * 16 + l16) * 32 + g * 8]);
#pragma unroll
      for (int ni = 0; ni < 4; ++ni) {
        b1f[ni] = *(const bf16x8*)(&B1src[(wc * 64 + ni * 16 + l16) * 32 + g * 8]);
        b3f[ni] = *(const bf16x8*)(&B3src[(wc * 64 + ni * 16 + l16) * 32 + g * 8]);
      }
#pragma unroll
      for (int mi = 0; mi < 4; ++mi)
#pragma unroll
        for (int ni = 0; ni < 4; ++ni) {
          acc1[mi][ni] = __builtin_amdgcn_mfma_f32_16x16x32_bf16(af[mi], b1f[ni], acc1[mi][ni], 0, 0, 0);
          acc3[mi][ni] = __builtin_amdgcn_mfma_f32_16x16x32_bf16(af[mi], b3f[ni], acc3[mi][ni], 0, 0, 0);
        }
    }
  }

#pragma unroll
  for (int mi = 0; mi < 4; ++mi)
#pragma unroll
    for (int ni = 0; ni < 4; ++ni) {
      const int col = n0 + wc * 64 + ni * 16 + l16;
#pragma unroll
      for (int r = 0; r < 4; ++r) {
        const int slot = m0 + wr * 64 + mi * 16 + g * 4 + r;
        float hv = bf2f(f2bf(acc1[mi][ni][r]));  // emulate H1 bf16 roundtrip (bit-identical)
        float sw = hv * sigf(hv);
        float val = sw * acc3[mi][ni][r];
        if constexpr (GATH) val = val * cwE[slot];
        G[(size_t)slot * N + col] = f2bf(val);
      }
    }
}

// ---------------- routed down-projection, z-batched: ffz[z][t] += G@B2^T ----------------
__global__ __launch_bounds__(256, 2) void k_gemmR2(const u16* __restrict__ A0, size_t az,
                                                   const u16* __restrict__ BT0, size_t bzs, int N, int K,
                                                   const int* __restrict__ gidx0,
                                                   const int* __restrict__ Mp0, float* __restrict__ ffA,
                                                   float* __restrict__ ffB) {
  int bx, by, bz;
  xcd_swz(bx, by, bz);
  const int z = bz;
  const int m0 = by * 128;
  if (m0 >= Mp0[z]) return;
  const int* gidxE = gidx0 + (size_t)z * RSTRIDE;
  const u16* A = A0 + (size_t)z * az;
  const u16* BT = BT0 + (size_t)z * bzs;
  float* ff = z ? ffB : ffA;

  __shared__ __align__(16) u16 As[2][8192], Bs[2][8192];
  const int tid = threadIdx.x, wid = tid >> 6, lane = tid & 63;
  const int l16 = lane & 15, g = lane >> 4;
  const int wr = wid >> 1, wc = wid & 1;
  const int n0 = bx * 128;
  const int srow = lane >> 2, scol = (lane & 3) * 8;
  const int slot0 = m0 + wid * 32 + srow;
  const u16* aS0 = A + (size_t)slot0 * K + scol;
  const u16* aS1 = A + (size_t)(slot0 + 16) * K + scol;
  const u16* bS0 = BT + (size_t)(n0 + wid * 32 + srow) * K + scol;
  const u16* bS1 = bS0 + (size_t)16 * K;

  const f32x4 zero4 = {0.f, 0.f, 0.f, 0.f};
  f32x4 acc[4][4];
#pragma unroll
  for (int mi = 0; mi < 4; ++mi)
#pragma unroll
    for (int ni = 0; ni < 4; ++ni) acc[mi][ni] = zero4;

  auto stage = [&](int b, int k0) {
    gload16(aS0 + k0, &As[b][wid * 1024]);
    gload16(aS1 + k0, &As[b][wid * 1024 + 512]);
    gload16(aS0 + k0 + 32, &As[b][4096 + wid * 1024]);
    gload16(aS1 + k0 + 32, &As[b][4096 + wid * 1024 + 512]);
    gload16(bS0 + k0, &Bs[b][wid * 1024]);
    gload16(bS1 + k0, &Bs[b][wid * 1024 + 512]);
    gload16(bS0 + k0 + 32, &Bs[b][4096 + wid * 1024]);
    gload16(bS1 + k0 + 32, &Bs[b][4096 + wid * 1024 + 512]);
  };
  auto compute = [&](int b) {
#pragma unroll
    for (int hh = 0; hh < 2; ++hh) {
      const u16* Asrc = &As[b][hh * 4096];
      const u16* Bsrc = &Bs[b][hh * 4096];
      bf16x8 af[4], bfr[4];
#pragma unroll
      for (int mi = 0; mi < 4; ++mi)
        af[mi] = *(const bf16x8*)(&Asrc[(wr * 64 + mi * 16 + l16) * 32 + g * 8]);
#pragma unroll
      for (int ni = 0; ni < 4; ++ni)
        bfr[ni] = *(const bf16x8*)(&Bsrc[(wc * 64 + ni * 16 + l16) * 32 + g * 8]);
#pragma unroll
      for (int mi = 0; mi < 4; ++mi)
#pragma unroll
        for (int ni = 0; ni < 4; ++ni)
          acc[mi][ni] = __builtin_amdgcn_mfma_f32_16x16x32_bf16(af[mi], bfr[ni], acc[mi][ni], 0, 0, 0);
    }
  };

  stage(0, 0);
  __syncthreads();
  for (int k0 = 0; k0 < K; k0 += 128) {
    if (k0 + 64 < K) stage(1, k0 + 64);
    compute(0);
    __syncthreads();
    if (k0 + 128 < K) stage(0, k0 + 128);
    compute(1);
    __syncthreads();
  }

#pragma unroll
  for (int mi = 0; mi < 4; ++mi)
#pragma unroll
    for (int ni = 0; ni < 4; ++ni) {
      const int col = n0 + wc * 64 + ni * 16 + l16;
#pragma unroll
      for (int r = 0; r < 4; ++r) {
        const int slot = m0 + wr * 64 + mi * 16 + g * 4 + r;
        int t = gidxE[slot];
        if (t >= 0) ff[(size_t)t * N + col] += acc[mi][ni][r];
      }
    }
}

// ---------------- split-precision GEMM: pre-split hi/lo globals; pipelined dbuf ----------------
// MODE 7: Cf = acc + segmented bias (QKV fused, N=3*DIMC)
// MODE 2: Cf = (acc+bias0)*gvec[col] + resid
template <int MODE>
__global__ __launch_bounds__(256, 2) void k_gemm3s(const u16* __restrict__ Ahg, const u16* __restrict__ Alg,
                                                   const u16* __restrict__ Bhg, const u16* __restrict__ Blg,
                                                   int M, int N, int K, float* __restrict__ Cf,
                                                   const float* __restrict__ bias0,
                                                   const float* __restrict__ bias1,
                                                   const float* __restrict__ bias2,
                                                   const float* __restrict__ gvec,
                                                   const float* __restrict__ resid) {
  int bxs, bys, bzs2;
  xcd_swz(bxs, bys, bzs2);
  __shared__ __align__(16) u16 Ahs[2][4096], Als[2][4096], Bhs[2][4096], Bls[2][4096];
  const int tid = threadIdx.x, wid = tid >> 6, lane = tid & 63;
  const int l16 = lane & 15, g = lane >> 4;
  const int wr = wid >> 1, wc = wid & 1;
  const int m0 = bys * 128, n0 = bxs * 128;
  const int srow = lane >> 2, scol = (lane & 3) * 8;
  const size_t aOff0 = (size_t)(m0 + wid * 32 + srow) * K + scol;
  const size_t aOff1 = aOff0 + (size_t)16 * K;
  const size_t bOff0 = (size_t)(n0 + wid * 32 + srow) * K + scol;
  const size_t bOff1 = bOff0 + (size_t)16 * K;

  const f32x4 zero4 = {0.f, 0.f, 0.f, 0.f};
  f32x4 acc[4][4];
#pragma unroll
  for (int mi = 0; mi < 4; ++mi)
#pragma unroll
    for (int ni = 0; ni < 4; ++ni) acc[mi][ni] = zero4;

  auto stage = [&](int b, int k0) {
    gload16(Ahg + aOff0 + k0, &Ahs[b][wid * 1024]);
    gload16(Ahg + aOff1 + k0, &Ahs[b][wid * 1024 + 512]);
    gload16(Alg + aOff0 + k0, &Als[b][wid * 1024]);
    gload16(Alg + aOff1 + k0, &Als[b][wid * 1024 + 512]);
    gload16(Bhg + bOff0 + k0, &Bhs[b][wid * 1024]);
    gload16(Bhg + bOff1 + k0, &Bhs[b][wid * 1024 + 512]);
    gload16(Blg + bOff0 + k0, &Bls[b][wid * 1024]);
    gload16(Blg + bOff1 + k0, &Bls[b][wid * 1024 + 512]);
  };
  auto compute = [&](int b) {
    bf16x8 bhf[4], blf[4];
#pragma unroll
    for (int ni = 0; ni < 4; ++ni) {
      bhf[ni] = *(const bf16x8*)(&Bhs[b][(wc * 64 + ni * 16 + l16) * 32 + g * 8]);
      blf[ni] = *(const bf16x8*)(&Bls[b][(wc * 64 + ni * 16 + l16) * 32 + g * 8]);
    }
#pragma unroll
    for (int mi = 0; mi < 4; ++mi) {
      bf16x8 ahf = *(const bf16x8*)(&Ahs[b][(wr * 64 + mi * 16 + l16) * 32 + g * 8]);
      bf16x8 alf = *(const bf16x8*)(&Als[b][(wr * 64 + mi * 16 + l16) * 32 + g * 8]);
#pragma unroll
      for (int ni = 0; ni < 4; ++ni) {
        acc[mi][ni] = __builtin_amdgcn_mfma_f32_16x16x32_bf16(alf, bhf[ni], acc[mi][ni], 0, 0, 0);
        acc[mi][ni] = __builtin_amdgcn_mfma_f32_16x16x32_bf16(ahf, blf[ni], acc[mi][ni], 0, 0, 0);
        acc[mi][ni] = __builtin_amdgcn_mfma_f32_16x16x32_bf16(ahf, bhf[ni], acc[mi][ni], 0, 0, 0);
      }
    }
  };

  stage(0, 0);
  __syncthreads();
  for (int k0 = 0; k0 < K; k0 += 64) {
    if (k0 + 32 < K) stage(1, k0 + 32);
    compute(0);
    __syncthreads();
    if (k0 + 64 < K) stage(0, k0 + 64);
    compute(1);
    __syncthreads();
  }

  const float* bp = bias0;
  if constexpr (MODE == 7) bp = (n0 < DIMC) ? bias0 : (n0 < 2 * DIMC ? bias1 : bias2);
#pragma unroll
  for (int mi = 0; mi < 4; ++mi)
#pragma unroll
    for (int ni = 0; ni < 4; ++ni) {
      const int col = n0 + wc * 64 + ni * 16 + l16;
      float bv = bp ? bp[col & (DIMC - 1)] : 0.f;
#pragma unroll
      for (int r = 0; r < 4; ++r) {
        const int row = m0 + wr * 64 + mi * 16 + g * 4 + r;
        float v = acc[mi][ni][r] + bv;
        if constexpr (MODE == 7) {
          Cf[(size_t)row * N + col] = v;
        } else {
          Cf[(size_t)row * N + col] = v * gvec[col] + resid[(size_t)row * N + col];
        }
      }
    }
}

// ---------------- flash attention: head->XCD pinned (bid%8 == head%8); pre-split K/V globals ----------------
__global__ __launch_bounds__(256, 3) void k_flash3(const u16* __restrict__ qh_g, const u16* __restrict__ ql_g,
                                                   const u16* __restrict__ kh_g, const u16* __restrict__ kl_g,
                                                   const u16* __restrict__ vth_g, const u16* __restrict__ vtl_g,
                                                   u16* __restrict__ oh_g, u16* __restrict__ ol_g) {
  __shared__ __align__(16) u16 Kh[4096], Kl[4096], Vh[128 * 40], Vl[128 * 40];
  __shared__ __align__(16) u16 Pah[4][16 * 40], Pal[4][16 * 40];
  const int tid = threadIdx.x, wid = tid >> 6, lane = tid & 63;
  const int l16 = lane & 15, g = lane >> 4;
  const int bid = blockIdx.x;
  const int h = (bid & 7) + ((bid >> 8) << 3);
  const int qb = (bid >> 3) & 31;
  const int r0 = qb * 64 + wid * 16;
  const size_t hOff = (size_t)h * HDIM;

  bf16x8 qfh[4], qfl[4];
#pragma unroll
  for (int kc = 0; kc < 4; ++kc) {
    const size_t qo = (size_t)(r0 + l16) * DIMC + hOff + kc * 32 + g * 8;
    qfh[kc] = *(const bf16x8*)(qh_g + qo);
    qfl[kc] = *(const bf16x8*)(ql_g + qo);
  }

  const int kr = tid >> 3, ke0 = (tid & 7) * 16;
  const int kswz = (kr & 7) << 4;
  const int kc0 = (ke0 * 2) ^ kswz, kc1 = (ke0 * 2 + 16) ^ kswz;
  char* khp = (char*)Kh + kr * 256;
  char* klp = (char*)Kl + kr * 256;
  const size_t kOff = (size_t)kr * DIMC + hOff + ke0;
  const int vr = tid >> 1, ve0 = (tid & 1) * 16;
  char* vhp = (char*)Vh + vr * 80 + ve0 * 2;
  char* vlp = (char*)Vl + vr * 80 + ve0 * 2;
  const size_t vOff = (size_t)(hOff + vr) * SEQ + ve0;

  u16x8 kH0, kH1, kL0, kL1, vH0, vH1, vL0, vL1;
  kH0 = *(const u16x8*)(kh_g + kOff);
  kH1 = *(const u16x8*)(kh_g + kOff + 8);
  kL0 = *(const u16x8*)(kl_g + kOff);
  kL1 = *(const u16x8*)(kl_g + kOff + 8);
  vH0 = *(const u16x8*)(vth_g + vOff);
  vH1 = *(const u16x8*)(vth_g + vOff + 8);
  vL0 = *(const u16x8*)(vtl_g + vOff);
  vL1 = *(const u16x8*)(vtl_g + vOff + 8);

  const f32x4 zero4 = {0.f, 0.f, 0.f, 0.f};
  f32x4 oacc[8];
#pragma unroll
  for (int db = 0; db < 8; ++db) oacc[db] = zero4;
  float mr[4], lr[4];
#pragma unroll
  for (int r = 0; r < 4; ++r) {
    mr[r] = -3.0e38f;
    lr[r] = 0.f;
  }

  for (int j0 = 0; j0 < SEQ; j0 += 32) {
    __syncthreads();
    *(u16x8*)(khp + kc0) = kH0;
    *(u16x8*)(khp + kc1) = kH1;
    *(u16x8*)(klp + kc0) = kL0;
    *(u16x8*)(klp + kc1) = kL1;
    *(u16x8*)(vhp) = vH0;
    *(u16x8*)(vhp + 16) = vH1;
    *(u16x8*)(vlp) = vL0;
    *(u16x8*)(vlp + 16) = vL1;
    __syncthreads();
    if (j0 + 32 < SEQ) {
      const size_t ko = kOff + (size_t)(j0 + 32) * DIMC;
      const size_t vo = vOff + j0 + 32;
      kH0 = *(const u16x8*)(kh_g + ko);
      kH1 = *(const u16x8*)(kh_g + ko + 8);
      kL0 = *(const u16x8*)(kl_g + ko);
      kL1 = *(const u16x8*)(kl_g + ko + 8);
      vH0 = *(const u16x8*)(vth_g + vo);
      vH1 = *(const u16x8*)(vth_g + vo + 8);
      vL0 = *(const u16x8*)(vtl_g + vo);
      vL1 = *(const u16x8*)(vtl_g + vo + 8);
    }
    f32x4 s0 = zero4, s1 = zero4;
    __builtin_amdgcn_s_setprio(1);
#pragma unroll
    for (int kc = 0; kc < 4; ++kc) {
      const int cb = (kc * 64 + g * 16) ^ ((l16 & 7) << 4);
      bf16x8 kh0 = *(const bf16x8*)((char*)Kh + l16 * 256 + cb);
      bf16x8 kl0 = *(const bf16x8*)((char*)Kl + l16 * 256 + cb);
      bf16x8 kh1 = *(const bf16x8*)((char*)Kh + (16 + l16) * 256 + cb);
      bf16x8 kl1 = *(const bf16x8*)((char*)Kl + (16 + l16) * 256 + cb);
      s0 = __builtin_amdgcn_mfma_f32_16x16x32_bf16(qfl[kc], kh0, s0, 0, 0, 0);
      s0 = __builtin_amdgcn_mfma_f32_16x16x32_bf16(qfh[kc], kl0, s0, 0, 0, 0);
      s0 = __builtin_amdgcn_mfma_f32_16x16x32_bf16(qfh[kc], kh0, s0, 0, 0, 0);
      s1 = __builtin_amdgcn_mfma_f32_16x16x32_bf16(qfl[kc], kh1, s1, 0, 0, 0);
      s1 = __builtin_amdgcn_mfma_f32_16x16x32_bf16(qfh[kc], kl1, s1, 0, 0, 0);
      s1 = __builtin_amdgcn_mfma_f32_16x16x32_bf16(qfh[kc], kh1, s1, 0, 0, 0);
    }
    __builtin_amdgcn_s_setprio(0);
    float corr[4];
#pragma unroll
    for (int r = 0; r < 4; ++r) {
      float tm = fmaxf(s0[r], s1[r]);
#pragma unroll
      for (int m = 1; m < 16; m <<= 1) tm = fmaxf(tm, __shfl_xor(tm, m));
      float mn = fmaxf(mr[r], tm);
      corr[r] = __expf(mr[r] - mn);
      mr[r] = mn;
      float p0 = __expf(s0[r] - mn);
      float p1 = __expf(s1[r] - mn);
      lr[r] = lr[r] * corr[r] + p0 + p1;
      u16 p0h = f2bf(p0), p1h = f2bf(p1);
      Pah[wid][(g * 4 + r) * 40 + l16] = p0h;
      Pah[wid][(g * 4 + r) * 40 + 16 + l16] = p1h;
      Pal[wid][(g * 4 + r) * 40 + l16] = f2bf(p0 - bf2f(p0h));
      Pal[wid][(g * 4 + r) * 40 + 16 + l16] = f2bf(p1 - bf2f(p1h));
    }
#pragma unroll
    for (int db = 0; db < 8; ++db)
#pragma unroll
      for (int r = 0; r < 4; ++r) oacc[db][r] *= corr[r];
    bf16x8 pfh = *(const bf16x8*)(&Pah[wid][l16 * 40 + g * 8]);
    bf16x8 pfl = *(const bf16x8*)(&Pal[wid][l16 * 40 + g * 8]);
    __builtin_amdgcn_s_setprio(1);
#pragma unroll
    for (int db = 0; db < 8; ++db) {
      const int row = db * 16 + l16;
      bf16x8 vh = *(const bf16x8*)((char*)Vh + row * 80 + g * 16);
      bf16x8 vl = *(const bf16x8*)((char*)Vl + row * 80 + g * 16);
      oacc[db] = __builtin_amdgcn_mfma_f32_16x16x32_bf16(pfl, vh, oacc[db], 0, 0, 0);
      oacc[db] = __builtin_amdgcn_mfma_f32_16x16x32_bf16(pfh, vl, oacc[db], 0, 0, 0);
      oacc[db] = __builtin_amdgcn_mfma_f32_16x16x32_bf16(pfh, vh, oacc[db], 0, 0, 0);
    }
    __builtin_amdgcn_s_setprio(0);
  }
#pragma unroll
  for (int r = 0; r < 4; ++r) {
#pragma unroll
    for (int m = 1; m < 16; m <<= 1) lr[r] += __shfl_xor(lr[r], m);
    lr[r] = 1.f / lr[r];
  }
#pragma unroll
  for (int db = 0; db < 8; ++db)
#pragma unroll
    for (int r = 0; r < 4; ++r) {
      float v = oacc[db][r] * lr[r];
      u16 hh, ll;
      splitf(v, hh, ll);
      const size_t idx = (size_t)(r0 + g * 4 + r) * DIMC + hOff + db * 16 + l16;
      oh_g[idx] = hh;
      ol_g[idx] = ll;
    }
}

// ---------------- final: out = g_mlp[col]*(ffA+ffB) + img   (img aliases out; in-place) ----------------
__global__ __launch_bounds__(256) void k_final(const float* __restrict__ ffA, const float* __restrict__ ffB,
                                               const float* img, const float* __restrict__ mod,
                                               float* out) {
  const float4* gm = (const float4*)(mod + 5 * DIMC);
  const int total = SEQ * DIMC / 4;
  const int stride = gridDim.x * blockDim.x;
  for (int i = blockIdx.x * blockDim.x + threadIdx.x; i < total; i += stride) {
    int col4 = i & (DIMC / 4 - 1);
    float4 gv = gm[col4];
    float4 fa = ((const float4*)ffA)[i];
    float4 fb = ((const float4*)ffB)[i];
    float4 iv = ((const float4*)img)[i];
    float4 ov;
    ov.x = gv.x * (fa.x + fb.x) + iv.x;
    ov.y = gv.y * (fa.y + fb.y) + iv.y;
    ov.z = gv.z * (fa.z + fb.z) + iv.z;
    ov.w = gv.w * (fa.w + fb.w) + iv.w;
    ((float4*)out)[i] = ov;
  }
}

extern "C" void kernel_launch(void* const* d_in, const int* in_sizes, int n_in, void* d_out, int out_size,
                              void* d_ws, size_t ws_size, hipStream_t stream) {
  (void)in_sizes; (void)n_in; (void)out_size; (void)ws_size;
  const float* image_tokens = (const float*)d_in[0];
  const float* adaln_input = (const float*)d_in[1];
  const float* W_ada = (const float*)d_in[2];
  const float* b_ada = (const float*)d_in[3];
  const float* Wq = (const float*)d_in[4];
  const float* bq = (const float*)d_in[5];
  const float* Wk = (const float*)d_in[6];
  const float* bk = (const float*)d_in[7];
  const float* Wv = (const float*)d_in[8];
  const float* bv = (const float*)d_in[9];
  const float* q_rms_w = (const float*)d_in[10];
  const float* k_rms_w = (const float*)d_in[11];
  const float* Wo = (const float*)d_in[12];
  const float* bo = (const float*)d_in[13];
  const float* gate_w = (const float*)d_in[14];
  const float* We1 = (const float*)d_in[15];
  const float* We3 = (const float*)d_in[16];
  const float* We2 = (const float*)d_in[17];
  const float* Ws1 = (const float*)d_in[18];
  const float* Ws3 = (const float*)d_in[19];
  const float* Ws2 = (const float*)d_in[20];

  // ---- workspace: ~229 MB; attention region aliased by MoE phase ----
  char* cur = (char*)d_ws;
  auto alloc = [&](size_t n) {
    char* p = cur;
    cur += (n + 255) & ~(size_t)255;
    return p;
  };
  float* modv = (float*)alloc((size_t)MOD6 * 4);
  float* adap = (float*)alloc((size_t)16 * MOD6 * 4);
  float* comb = (float*)alloc((size_t)SEQ * NEXP * 4);
  int* gidx = (int*)alloc((size_t)NEXP * RSTRIDE * 4);
  float* cw = (float*)alloc((size_t)NEXP * RSTRIDE * 4);
  int* Mpad = (int*)alloc((size_t)NEXP * 4);
  // attention region start (~184.6MB contiguous):
  u16* xh = (u16*)alloc((size_t)SEQ * DIMC * 2);
  u16* xl = (u16*)alloc((size_t)SEQ * DIMC * 2);
  u16* wTh3 = (u16*)alloc((size_t)3 * DIMC * DIMC * 2);
  u16* wTl3 = (u16*)alloc((size_t)3 * DIMC * DIMC * 2);
  float* tf3 = (float*)alloc((size_t)SEQ * 3 * DIMC * 4);
  u16* qhb = (u16*)alloc((size_t)SEQ * DIMC * 2);
  u16* qlb = (u16*)alloc((size_t)SEQ * DIMC * 2);
  u16* khb = (u16*)alloc((size_t)SEQ * DIMC * 2);
  u16* klb = (u16*)alloc((size_t)SEQ * DIMC * 2);
  u16* vth = (u16*)alloc((size_t)SEQ * DIMC * 2);
  u16* vtl = (u16*)alloc((size_t)SEQ * DIMC * 2);
  u16* aoh = (u16*)alloc((size_t)SEQ * DIMC * 2);
  u16* aol = (u16*)alloc((size_t)SEQ * DIMC * 2);
  // end attention region
  u16* x_act = (u16*)alloc((size_t)SEQ * DIMC * 2);
  float* ff = (float*)alloc((size_t)SEQ * DIMC * 4);
  float* ffB = (float*)alloc((size_t)SEQ * DIMC * 4);
  float* img = (float*)d_out;  // MODE2 writes before any read
  // MoE-phase aliases into the dead attention region:
  const size_t BZ = (size_t)HIDC * DIMC;
  const size_t CZ = (size_t)RSTRIDE * HIDC;
  u16* moe0 = xh;
  u16* wbufE1 = moe0;
  u16* wbufE3 = moe0 + 2 * BZ;
  u16* G2 = moe0 + 4 * BZ;
  u16* wbufS1 = moe0;
  u16* wbufS3 = moe0 + (size_t)HSH * DIMC;
  u16* wbufS2 = moe0 + (size_t)2 * HSH * DIMC;
  u16* Gs = moe0 + (size_t)3 * HSH * DIMC;

  dim3 blk(256);

  // adaLN modulation vector
  k_adaln_p<<<dim3(MOD6 / 256, 16), blk, 0, stream>>>(adaln_input, W_ada, adap);
  k_adaln_r<<<dim3(MOD6 / 256), blk, 0, stream>>>(adap, b_ada, modv);

  // ---- attention branch (f32-accurate; QKV fused into one N=6144 GEMM) ----
  k_ln_mod_split<<<dim3(SEQ), blk, 0, stream>>>(image_tokens, modv, 0, DIMC, xh, xl);
  k_transpose_s<<<dim3(DIMC / 32, DIMC / 32), blk, 0, stream>>>(Wq, wTh3, wTl3, DIMC, DIMC, DIMC);
  k_transpose_s<<<dim3(DIMC / 32, DIMC / 32), blk, 0, stream>>>(
      Wk, wTh3 + (size_t)DIMC * DIMC, wTl3 + (size_t)DIMC * DIMC, DIMC, DIMC, DIMC);
  k_transpose_s<<<dim3(DIMC / 32, DIMC / 32), blk, 0, stream>>>(
      Wv, wTh3 + (size_t)2 * DIMC * DIMC, wTl3 + (size_t)2 * DIMC * DIMC, DIMC, DIMC, DIMC);
  k_gemm3s<7><<<dim3(3 * DIMC / 128, SEQ / 128), blk, 0, stream>>>(
      xh, xl, wTh3, wTl3, SEQ, 3 * DIMC, DIMC, tf3, bq, bk, bv, nullptr, nullptr);
  k_rms_split<<<dim3(SEQ), blk, 0, stream>>>(tf3, 3 * DIMC, q_rms_w, 0.08838834764831845f, qhb, qlb);
  k_rms_split<<<dim3(SEQ), blk, 0, stream>>>(tf3 + DIMC, 3 * DIMC, k_rms_w, 1.f, khb, klb);
  k_transpose_s<<<dim3(DIMC / 32, SEQ / 32), blk, 0, stream>>>(tf3 + 2 * DIMC, vth, vtl, SEQ, DIMC,
                                                               3 * DIMC);
  k_flash3<<<dim3(SEQ / 64 * NHEAD), blk, 0, stream>>>(qhb, qlb, khb, klb, vth, vtl, aoh, aol);
  k_transpose_s<<<dim3(DIMC / 32, DIMC / 32), blk, 0, stream>>>(Wo, wTh3, wTl3, DIMC, DIMC, DIMC);
  k_gemm3s<2><<<dim3(DIMC / 128, SEQ / 128), blk, 0, stream>>>(
      aoh, aol, wTh3, wTl3, SEQ, DIMC, DIMC, img, bo, nullptr, nullptr, modv + 2 * DIMC, image_tokens);

  // ---- MoE branch ----
  k_ln_mod<<<dim3(SEQ), blk, 0, stream>>>(img, modv, 3 * DIMC, 4 * DIMC, x_act);
  k_gate<<<dim3(SEQ), blk, 0, stream>>>(img, modv, gate_w, comb);
  k_route<<<dim3(1), blk, 0, stream>>>(comb, gidx, cw, Mpad);
  hipMemsetAsync(ffB, 0, (size_t)SEQ * DIMC * 4, stream);  // ffB accumulator for odd experts

  // shared expert (fused up-proj; down-proj initializes ff with a plain store)
  k_transpose<<<dim3(HSH / 32, DIMC / 32), blk, 0, stream>>>(Ws1, wbufS1, DIMC, HSH, HSH, 0, 0);
  k_transpose<<<dim3(HSH / 32, DIMC / 32), blk, 0, stream>>>(Ws3, wbufS3, DIMC, HSH, HSH, 0, 0);
  k_gemmUP<0><<<dim3(HSH / 128, SEQ / 128, 1), blk, 0, stream>>>(
      x_act, wbufS1, wbufS3, 0, HSH, DIMC, nullptr, nullptr, nullptr, Gs, 0);
  k_transpose<<<dim3(DIMC / 32, HSH / 32), blk, 0, stream>>>(Ws2, wbufS2, HSH, DIMC, DIMC, 0, 0);
  k_gemmD<<<dim3(DIMC / 128, SEQ / 128), blk, 0, stream>>>(Gs, wbufS2, SEQ, DIMC, HSH, ff);

  // routed experts, z-batched pairs (up-proj fused; down-proj z-batched via split ff/ffB)
  const size_t WE = (size_t)DIMC * HIDC;
  for (int p = 0; p < 2; ++p) {
    const int e0 = p * 2;
    k_transpose<<<dim3(HIDC / 32, DIMC / 32, 2), blk, 0, stream>>>(We1 + (size_t)e0 * WE, wbufE1,
                                                                   DIMC, HIDC, HIDC, WE, BZ);
    k_transpose<<<dim3(HIDC / 32, DIMC / 32, 2), blk, 0, stream>>>(We3 + (size_t)e0 * WE, wbufE3,
                                                                   DIMC, HIDC, HIDC, WE, BZ);
    k_gemmUP<1><<<dim3(HIDC / 128, SEQ / 128, 2), blk, 0, stream>>>(
        x_act, wbufE1, wbufE3, BZ, HIDC, DIMC, gidx + e0 * RSTRIDE, cw + e0 * RSTRIDE, Mpad + e0, G2,
        CZ);
    k_transpose<<<dim3(DIMC / 32, HIDC / 32, 2), blk, 0, stream>>>(We2 + (size_t)e0 * WE, wbufE1,
                                                                   HIDC, DIMC, DIMC, WE, BZ);
    k_gemmR2<<<dim3(DIMC / 128, SEQ / 128, 2), blk, 0, stream>>>(
        G2, CZ, wbufE1, BZ, DIMC, HIDC, gidx + e0 * RSTRIDE, Mpad + e0, ff, ffB);
  }

  k_final<<<dim3(1024), blk, 0, stream>>>(ff, ffB, img, modv, (float*)d_out);
}